// Round 8
// baseline (272.462 us; speedup 1.0000x reference)
//
#include <hip/hip_runtime.h>
#include <hip/hip_bf16.h>
#include <math.h>

// Problem dims (fixed)
#define C_IN 256
#define HW 128          // H = W = 128
#define NPIX (HW*HW)    // 16384
#define DIM_LOI 128
#define N_LINES 16000
#define N_PTS0 32
#define N_PTS1 8
#define DIM_FC 1024
#define N_LABELS 3

typedef __attribute__((ext_vector_type(8))) short short8;   // 8 bf16 = 4 VGPRs
typedef __attribute__((ext_vector_type(4))) float f32x4;

// ---------------------------------------------------------------------------
// Transpose + bf16: features (256, 16384) fp32 -> featsT (16384, 256) bf16
// ---------------------------------------------------------------------------
__global__ __launch_bounds__(256) void transpose_feats(
    const float* __restrict__ feats,
    __hip_bfloat16* __restrict__ featsT)
{
    __shared__ float tile[64][65];
    const int t = threadIdx.x;
    const int p0 = blockIdx.x * 64;
    const int c0 = blockIdx.y * 64;
#pragma unroll
    for (int i = 0; i < 4; ++i) {
        int c = (t >> 4) + i * 16;
        int p4 = (t & 15) * 4;
        float4 v = *(const float4*)(feats + (size_t)(c0 + c) * NPIX + p0 + p4);
        tile[c][p4 + 0] = v.x;
        tile[c][p4 + 1] = v.y;
        tile[c][p4 + 2] = v.z;
        tile[c][p4 + 3] = v.w;
    }
    __syncthreads();
#pragma unroll
    for (int i = 0; i < 2; ++i) {
        int p = (t >> 3) + i * 32;
        int cc = (t & 7) * 8;
        union { __hip_bfloat16 h[8]; uint4 u4; } pk;
#pragma unroll
        for (int j = 0; j < 8; ++j) pk.h[j] = __float2bfloat16(tile[cc + j][p]);
        *(uint4*)(featsT + (size_t)(p0 + p) * C_IN + c0 + cc) = pk.u4;
    }
}

// ---------------------------------------------------------------------------
// Kernel 2: line pool. 256 thr = 4 lines x 64 lanes; lane owns 2 channels
// (uint gathers). feat layout k' = p*128 + c (coalesced uint stores);
// w1 is permuted to the same k order.
// ---------------------------------------------------------------------------
__global__ __launch_bounds__(256) void pool_kernel(
    const __hip_bfloat16* __restrict__ loi,   // (NPIX, 128) bf16 channel-last
    const float* __restrict__ lines,          // (N_LINES, 4)
    __hip_bfloat16* __restrict__ feat)        // (N_LINES, 1024), k' = p*128+c
{
    __shared__ int   offs[4][N_PTS0][4];      // uint-index base (elements/2)
    __shared__ float wts[4][N_PTS0][4];
    const int g = threadIdx.x >> 6;   // line group in block
    const int t = threadIdx.x & 63;   // lane; owns channels 2t, 2t+1
    const int l = blockIdx.x * 4 + g;

    if (t < N_PTS0) {
        int j = t;
        float tt = (float)j * (1.0f / 31.0f);
        float U0 = lines[4 * l + 0], U1 = lines[4 * l + 1];
        float V0 = lines[4 * l + 2], V1 = lines[4 * l + 3];
        float px = U0 * tt + V0 * (1.0f - tt) - 0.5f;
        float py = U1 * tt + V1 * (1.0f - tt) - 0.5f;
        float px0 = fminf(fmaxf(floorf(px), 0.0f), 127.0f);
        float py0 = fminf(fmaxf(floorf(py), 0.0f), 127.0f);
        float px1 = fminf(fmaxf(px0 + 1.0f, 0.0f), 127.0f);
        float py1 = fminf(fmaxf(py0 + 1.0f, 0.0f), 127.0f);
        int ix0 = (int)px0, iy0 = (int)py0, ix1 = (int)px1, iy1 = (int)py1;
        float wx0 = px1 - px, wx1 = px - px0;
        float wy0 = py1 - py, wy1 = py - py0;
        offs[g][j][0] = (iy0 * HW + ix0) * 64;
        offs[g][j][1] = (iy1 * HW + ix0) * 64;
        offs[g][j][2] = (iy0 * HW + ix1) * 64;
        offs[g][j][3] = (iy1 * HW + ix1) * 64;
        wts[g][j][0] = wy0 * wx0;
        wts[g][j][1] = wy1 * wx0;
        wts[g][j][2] = wy0 * wx1;
        wts[g][j][3] = wy1 * wx1;
    }
    __syncthreads();

    const unsigned int* loi32 = (const unsigned int*)loi;
    unsigned int* featw = (unsigned int*)(feat + (size_t)l * (N_PTS1 * DIM_LOI));

#pragma unroll
    for (int p = 0; p < N_PTS1; ++p) {
        float b0 = -INFINITY, b1 = -INFINITY;
#pragma unroll
        for (int q = 0; q < 4; ++q) {
            int j = p * 4 + q;
            unsigned int v0 = loi32[offs[g][j][0] + t];
            unsigned int v1 = loi32[offs[g][j][1] + t];
            unsigned int v2 = loi32[offs[g][j][2] + t];
            unsigned int v3 = loi32[offs[g][j][3] + t];
            float w0 = wts[g][j][0], w1 = wts[g][j][1];
            float w2 = wts[g][j][2], w3 = wts[g][j][3];
            float sl = w0 * __uint_as_float(v0 << 16)
                     + w1 * __uint_as_float(v1 << 16)
                     + w2 * __uint_as_float(v2 << 16)
                     + w3 * __uint_as_float(v3 << 16);
            float sh = w0 * __uint_as_float(v0 & 0xffff0000u)
                     + w1 * __uint_as_float(v1 & 0xffff0000u)
                     + w2 * __uint_as_float(v2 & 0xffff0000u)
                     + w3 * __uint_as_float(v3 & 0xffff0000u);
            b0 = fmaxf(b0, sl);
            b1 = fmaxf(b1, sh);
        }
        union { __hip_bfloat16 h[2]; unsigned int u; } pk;
        pk.h[0] = __float2bfloat16(b0);
        pk.h[1] = __float2bfloat16(b1);
        featw[p * 64 + t] = pk.u;   // element p*128 + 2t
    }
}

// ---------------------------------------------------------------------------
// fp32 -> bf16 conversion
// ---------------------------------------------------------------------------
__global__ __launch_bounds__(256) void to_bf16(
    const float* __restrict__ src, __hip_bfloat16* __restrict__ dst, int n4)
{
    int i = blockIdx.x * blockDim.x + threadIdx.x;
    if (i < n4) {
        float4 v = *(const float4*)(src + (size_t)i * 4);
        dst[(size_t)i * 4 + 0] = __float2bfloat16(v.x);
        dst[(size_t)i * 4 + 1] = __float2bfloat16(v.y);
        dst[(size_t)i * 4 + 2] = __float2bfloat16(v.z);
        dst[(size_t)i * 4 + 3] = __float2bfloat16(v.w);
    }
}

// ---------------------------------------------------------------------------
// permute_w1: k = c*8+p -> k' = p*128+c, coalesced reads via LDS staging.
// ---------------------------------------------------------------------------
__global__ __launch_bounds__(256) void permute_w1(
    const float* __restrict__ w1, __hip_bfloat16* __restrict__ w1p)
{
    __shared__ float row[1024];
    const int n = blockIdx.x;
    const int t = threadIdx.x;
    ((float4*)row)[t] = ((const float4*)(w1 + (size_t)n * 1024))[t];
    __syncthreads();
    unsigned int* dst = (unsigned int*)(w1p + (size_t)n * 1024);
#pragma unroll
    for (int pass = 0; pass < 2; ++pass) {
        int j = pass * 256 + t;        // uint index; elements 2j, 2j+1
        int k0 = 2 * j, k1 = 2 * j + 1;
        float v0 = row[(k0 & 127) * 8 + (k0 >> 7)];
        float v1 = row[(k1 & 127) * 8 + (k1 >> 7)];
        union { __hip_bfloat16 h[2]; unsigned int u; } pk;
        pk.h[0] = __float2bfloat16(v0);
        pk.h[1] = __float2bfloat16(v1);
        dst[j] = pk.u;
    }
}

// ---------------------------------------------------------------------------
// init_out: logits[l][j] = b3[j]  (GEMM2 epilogue atomicAdds partials on top)
// ---------------------------------------------------------------------------
__global__ __launch_bounds__(256) void init_out(
    const float* __restrict__ b3, float* __restrict__ out)
{
    int i = blockIdx.x * 256 + threadIdx.x;
    if (i < N_LINES * N_LABELS) out[i] = b3[i % 3];
}

// ---------------------------------------------------------------------------
// MFMA bf16 GEMM, BK=64 (R6-exact core — replay-stable).
// 128x128 tile, 4 waves 2x2, each wave 4x4 of 16x16x32 MFMA.
// MODE 0: out[m][n] = relu(sum + bias[n]) as bf16.
// MODE 1 (head-fused): never materializes the output; computes
//   logits[m][j] += sum_n relu(sum + bias[n]) * w3[j][n]  via per-quad
//   shuffle reduction + fp32 atomicAdd (init_out pre-loads b3).
// XCD-aware swizzle: lid%8 = XCD, n fastest -> A-tile reused within one XCD.
// ---------------------------------------------------------------------------
template <int MODE>
__global__ __launch_bounds__(256) void mfma_gemm(
    const __hip_bfloat16* __restrict__ A,   // (M, K) row-major
    const __hip_bfloat16* __restrict__ B,   // (N, K) row-major (= B^T)
    const float* __restrict__ bias,         // (N)
    __hip_bfloat16* __restrict__ out,       // (M, N)  [MODE 0]
    int M, int N, int K, int n_tiles,
    const float* __restrict__ w3,           // (3, N)  [MODE 1]
    float* __restrict__ logits)             // (M, 3)  [MODE 1]
{
    __shared__ __hip_bfloat16 As[128 * 64];   // 16 KB
    __shared__ __hip_bfloat16 Bs[128 * 64];   // 16 KB
    const int tid  = threadIdx.x;
    const int lane = tid & 63;
    const int wave = tid >> 6;
    const int wr = wave >> 1, wc = wave & 1;    // 2x2 wave grid
    const int quad = lane >> 4;
    const int l16  = lane & 15;

    // XCD-aware relabel (grid must be divisible by 8)
    const int lid = blockIdx.x;
    const int per = gridDim.x >> 3;
    const int g   = (lid & 7) * per + (lid >> 3);
    const int n0 = (g % n_tiles) * 128;
    const int m0 = (g / n_tiles) * 128;

    f32x4 acc[4][4];
#pragma unroll
    for (int i = 0; i < 4; ++i)
#pragma unroll
        for (int j = 0; j < 4; ++j) { f32x4 z = {0.f, 0.f, 0.f, 0.f}; acc[i][j] = z; }

    for (int k0 = 0; k0 < K; k0 += 64) {
        // ---- stage A,B 128x64 tiles: 4 sites x 256 thr x 16 B each ----
#pragma unroll
        for (int s = 0; s < 4; ++s) {
            int li   = s * 256 + tid;          // chunk 0..1023
            int row  = (li & 511) >> 2;        // 0..127
            int ke   = (li >> 9) * 32 + (li & 3) * 8;  // k element offset 0..63
            const __hip_bfloat16* ga = A + (size_t)(m0 + row) * K + k0 + ke;
            const __hip_bfloat16* gb = B + (size_t)(n0 + row) * K + k0 + ke;
            int chunk = s * 256 + (tid & ~63); // wave-uniform base chunk
            __builtin_amdgcn_global_load_lds(
                (const __attribute__((address_space(1))) unsigned int*)ga,
                (__attribute__((address_space(3))) unsigned int*)(As + chunk * 8),
                16, 0, 0);
            __builtin_amdgcn_global_load_lds(
                (const __attribute__((address_space(1))) unsigned int*)gb,
                (__attribute__((address_space(3))) unsigned int*)(Bs + chunk * 8),
                16, 0, 0);
        }
        __syncthreads();

        // ---- two 32-k halves: fragments + MFMA ----
#pragma unroll
        for (int kh = 0; kh < 2; ++kh) {
            const short* ap = (const short*)As + kh * 4096;
            const short* bp = (const short*)Bs + kh * 4096;
            short8 af[4], bf[4];
#pragma unroll
            for (int mt = 0; mt < 4; ++mt) {
                int row = wr * 64 + mt * 16 + l16;
                af[mt] = *(const short8*)(ap + row * 32 + quad * 8);
            }
#pragma unroll
            for (int nt = 0; nt < 4; ++nt) {
                int row = wc * 64 + nt * 16 + l16;
                bf[nt] = *(const short8*)(bp + row * 32 + quad * 8);
            }
#pragma unroll
            for (int mt = 0; mt < 4; ++mt)
#pragma unroll
                for (int nt = 0; nt < 4; ++nt)
                    acc[mt][nt] = __builtin_amdgcn_mfma_f32_16x16x32_bf16(
                        af[mt], bf[nt], acc[mt][nt], 0, 0, 0);
        }
        __syncthreads();
    }

    if (MODE == 0) {
        // ---- epilogue: C row = quad*4 + r, col = l16 ----
#pragma unroll
        for (int nt = 0; nt < 4; ++nt) {
            int n = n0 + wc * 64 + nt * 16 + l16;
            float bv = bias[n];
#pragma unroll
            for (int mt = 0; mt < 4; ++mt) {
                int mbase = m0 + wr * 64 + mt * 16 + quad * 4;
#pragma unroll
                for (int r = 0; r < 4; ++r) {
                    float v = acc[mt][nt][r] + bv;
                    v = v > 0.0f ? v : 0.0f;
                    out[(size_t)(mbase + r) * N + n] = (__hip_bfloat16)v;
                }
            }
        }
    } else {
        // ---- head-fused epilogue: partial logits + reduce + atomicAdd ----
#pragma unroll
        for (int mt = 0; mt < 4; ++mt) {
            float s[4][3];
#pragma unroll
            for (int r = 0; r < 4; ++r) { s[r][0] = 0.f; s[r][1] = 0.f; s[r][2] = 0.f; }
#pragma unroll
            for (int nt = 0; nt < 4; ++nt) {
                int n = n0 + wc * 64 + nt * 16 + l16;
                float bv  = bias[n];
                float w30 = w3[n];
                float w31 = w3[DIM_FC + n];
                float w32 = w3[2 * DIM_FC + n];
#pragma unroll
                for (int r = 0; r < 4; ++r) {
                    float v = acc[mt][nt][r] + bv;
                    v = v > 0.0f ? v : 0.0f;
                    s[r][0] += v * w30;
                    s[r][1] += v * w31;
                    s[r][2] += v * w32;
                }
            }
            // reduce over the 16 lanes of this quad (l16 bits 0..3)
#pragma unroll
            for (int r = 0; r < 4; ++r)
#pragma unroll
                for (int j = 0; j < 3; ++j) {
                    float v = s[r][j];
                    v += __shfl_xor(v, 1);
                    v += __shfl_xor(v, 2);
                    v += __shfl_xor(v, 4);
                    v += __shfl_xor(v, 8);
                    s[r][j] = v;
                }
            if (l16 == 0) {
                int mbase = m0 + wr * 64 + mt * 16 + quad * 4;
#pragma unroll
                for (int r = 0; r < 4; ++r)
#pragma unroll
                    for (int j = 0; j < 3; ++j)
                        atomicAdd(logits + (size_t)(mbase + r) * 3 + j, s[r][j]);
            }
        }
    }
}

// ---------------------------------------------------------------------------
extern "C" void kernel_launch(void* const* d_in, const int* in_sizes, int n_in,
                              void* d_out, int out_size, void* d_ws, size_t ws_size,
                              hipStream_t stream) {
    const float* features = (const float*)d_in[0];  // (1,256,128,128)
    const float* lines    = (const float*)d_in[1];  // (16000,4)
    const float* w_fc1    = (const float*)d_in[2];  // (128,256)
    const float* b_fc1    = (const float*)d_in[3];  // (128)
    const float* w1       = (const float*)d_in[4];  // (1024,1024)
    const float* b1       = (const float*)d_in[5];  // (1024)
    const float* w2       = (const float*)d_in[6];  // (1024,1024)
    const float* b2       = (const float*)d_in[7];  // (1024)
    const float* w3       = (const float*)d_in[8];  // (3,1024)
    const float* b3       = (const float*)d_in[9];  // (3)
    float* out = (float*)d_out;

    char* ws = (char*)d_ws;
    __hip_bfloat16* loi    = (__hip_bfloat16*)ws;
    __hip_bfloat16* featb  = (__hip_bfloat16*)(ws + (size_t)8 * 1024 * 1024);
    __hip_bfloat16* x1b    = (__hip_bfloat16*)(ws + (size_t)40 * 1024 * 1024);
    __hip_bfloat16* w1b    = (__hip_bfloat16*)(ws + (size_t)72 * 1024 * 1024);
    __hip_bfloat16* w2b    = (__hip_bfloat16*)(ws + (size_t)74 * 1024 * 1024);
    __hip_bfloat16* featsT = (__hip_bfloat16*)(ws + (size_t)76 * 1024 * 1024);
    __hip_bfloat16* wfc1b  = (__hip_bfloat16*)(ws + (size_t)84 * 1024 * 1024);

    // 0) precision conversions / permutations
    transpose_feats<<<dim3(NPIX / 64, C_IN / 64), 256, 0, stream>>>(features, featsT);
    to_bf16<<<dim3((DIM_LOI * C_IN / 4 + 255) / 256), 256, 0, stream>>>(w_fc1, wfc1b, DIM_LOI * C_IN / 4);
    permute_w1<<<dim3(DIM_FC), 256, 0, stream>>>(w1, w1b);
    to_bf16<<<dim3((DIM_FC * DIM_FC / 4 + 255) / 256), 256, 0, stream>>>(w2, w2b, DIM_FC * DIM_FC / 4);
    init_out<<<dim3((N_LINES * N_LABELS + 255) / 256), 256, 0, stream>>>(b3, out);

    // 1) conv1x1 as MFMA GEMM (grid 128, 1 n-tile, K=256 -> 4 iters)
    mfma_gemm<0><<<dim3(NPIX / 128), 256, 0, stream>>>(
        featsT, wfc1b, b_fc1, loi, NPIX, DIM_LOI, C_IN, 1, nullptr, nullptr);

    // 2) line pooling -> featb (16000,1024) bf16, k' = p*128+c
    pool_kernel<<<dim3(N_LINES / 4), 256, 0, stream>>>(loi, lines, featb);

    // 3) x1 = relu(feat @ w1p^T + b1)   grid 1000 = 125 m x 8 n
    mfma_gemm<0><<<dim3((N_LINES / 128) * (DIM_FC / 128)), 256, 0, stream>>>(
        featb, w1b, b1, x1b, N_LINES, DIM_FC, DIM_FC, DIM_FC / 128, nullptr, nullptr);

    // 4) logits += relu(x1 @ w2^T + b2) @ w3^T   (head fused; x2 never stored)
    mfma_gemm<1><<<dim3((N_LINES / 128) * (DIM_FC / 128)), 256, 0, stream>>>(
        x1b, w2b, b2, nullptr, N_LINES, DIM_FC, DIM_FC, DIM_FC / 128, w3, out);
}

// Round 9
// 243.188 us; speedup vs baseline: 1.1204x; 1.1204x over previous
//
#include <hip/hip_runtime.h>
#include <hip/hip_bf16.h>
#include <math.h>

// Problem dims (fixed)
#define C_IN 256
#define HW 128          // H = W = 128
#define NPIX (HW*HW)    // 16384
#define DIM_LOI 128
#define N_LINES 16000
#define N_PTS0 32
#define N_PTS1 8
#define DIM_FC 1024
#define N_LABELS 3

typedef __attribute__((ext_vector_type(8))) short short8;    // 8 bf16 = 4 VGPRs
typedef __attribute__((ext_vector_type(16))) float f32x16;   // 32x32 acc

// ---------------------------------------------------------------------------
// Transpose + bf16: features (256, 16384) fp32 -> featsT (16384, 256) bf16
// ---------------------------------------------------------------------------
__global__ __launch_bounds__(256) void transpose_feats(
    const float* __restrict__ feats,
    __hip_bfloat16* __restrict__ featsT)
{
    __shared__ float tile[64][65];
    const int t = threadIdx.x;
    const int p0 = blockIdx.x * 64;
    const int c0 = blockIdx.y * 64;
#pragma unroll
    for (int i = 0; i < 4; ++i) {
        int c = (t >> 4) + i * 16;
        int p4 = (t & 15) * 4;
        float4 v = *(const float4*)(feats + (size_t)(c0 + c) * NPIX + p0 + p4);
        tile[c][p4 + 0] = v.x;
        tile[c][p4 + 1] = v.y;
        tile[c][p4 + 2] = v.z;
        tile[c][p4 + 3] = v.w;
    }
    __syncthreads();
#pragma unroll
    for (int i = 0; i < 2; ++i) {
        int p = (t >> 3) + i * 32;
        int cc = (t & 7) * 8;
        union { __hip_bfloat16 h[8]; uint4 u4; } pk;
#pragma unroll
        for (int j = 0; j < 8; ++j) pk.h[j] = __float2bfloat16(tile[cc + j][p]);
        *(uint4*)(featsT + (size_t)(p0 + p) * C_IN + c0 + cc) = pk.u4;
    }
}

// ---------------------------------------------------------------------------
// Line pool. 256 thr = 4 lines x 64 lanes; lane owns 2 channels (uint
// gathers). feat layout k' = p*128 + c; w1 permuted to the same k order.
// ---------------------------------------------------------------------------
__global__ __launch_bounds__(256) void pool_kernel(
    const __hip_bfloat16* __restrict__ loi,   // (NPIX, 128) bf16 channel-last
    const float* __restrict__ lines,          // (N_LINES, 4)
    __hip_bfloat16* __restrict__ feat)        // (N_LINES, 1024), k' = p*128+c
{
    __shared__ int   offs[4][N_PTS0][4];      // uint-index base (elements/2)
    __shared__ float wts[4][N_PTS0][4];
    const int g = threadIdx.x >> 6;   // line group in block
    const int t = threadIdx.x & 63;   // lane; owns channels 2t, 2t+1
    const int l = blockIdx.x * 4 + g;

    if (t < N_PTS0) {
        int j = t;
        float tt = (float)j * (1.0f / 31.0f);
        float U0 = lines[4 * l + 0], U1 = lines[4 * l + 1];
        float V0 = lines[4 * l + 2], V1 = lines[4 * l + 3];
        float px = U0 * tt + V0 * (1.0f - tt) - 0.5f;
        float py = U1 * tt + V1 * (1.0f - tt) - 0.5f;
        float px0 = fminf(fmaxf(floorf(px), 0.0f), 127.0f);
        float py0 = fminf(fmaxf(floorf(py), 0.0f), 127.0f);
        float px1 = fminf(fmaxf(px0 + 1.0f, 0.0f), 127.0f);
        float py1 = fminf(fmaxf(py0 + 1.0f, 0.0f), 127.0f);
        int ix0 = (int)px0, iy0 = (int)py0, ix1 = (int)px1, iy1 = (int)py1;
        float wx0 = px1 - px, wx1 = px - px0;
        float wy0 = py1 - py, wy1 = py - py0;
        offs[g][j][0] = (iy0 * HW + ix0) * 64;
        offs[g][j][1] = (iy1 * HW + ix0) * 64;
        offs[g][j][2] = (iy0 * HW + ix1) * 64;
        offs[g][j][3] = (iy1 * HW + ix1) * 64;
        wts[g][j][0] = wy0 * wx0;
        wts[g][j][1] = wy1 * wx0;
        wts[g][j][2] = wy0 * wx1;
        wts[g][j][3] = wy1 * wx1;
    }
    __syncthreads();

    const unsigned int* loi32 = (const unsigned int*)loi;
    unsigned int* featw = (unsigned int*)(feat + (size_t)l * (N_PTS1 * DIM_LOI));

#pragma unroll
    for (int p = 0; p < N_PTS1; ++p) {
        float b0 = -INFINITY, b1 = -INFINITY;
#pragma unroll
        for (int q = 0; q < 4; ++q) {
            int j = p * 4 + q;
            unsigned int v0 = loi32[offs[g][j][0] + t];
            unsigned int v1 = loi32[offs[g][j][1] + t];
            unsigned int v2 = loi32[offs[g][j][2] + t];
            unsigned int v3 = loi32[offs[g][j][3] + t];
            float w0 = wts[g][j][0], w1 = wts[g][j][1];
            float w2 = wts[g][j][2], w3 = wts[g][j][3];
            float sl = w0 * __uint_as_float(v0 << 16)
                     + w1 * __uint_as_float(v1 << 16)
                     + w2 * __uint_as_float(v2 << 16)
                     + w3 * __uint_as_float(v3 << 16);
            float sh = w0 * __uint_as_float(v0 & 0xffff0000u)
                     + w1 * __uint_as_float(v1 & 0xffff0000u)
                     + w2 * __uint_as_float(v2 & 0xffff0000u)
                     + w3 * __uint_as_float(v3 & 0xffff0000u);
            b0 = fmaxf(b0, sl);
            b1 = fmaxf(b1, sh);
        }
        union { __hip_bfloat16 h[2]; unsigned int u; } pk;
        pk.h[0] = __float2bfloat16(b0);
        pk.h[1] = __float2bfloat16(b1);
        featw[p * 64 + t] = pk.u;   // element p*128 + 2t
    }
}

// ---------------------------------------------------------------------------
// fp32 -> bf16 conversion
// ---------------------------------------------------------------------------
__global__ __launch_bounds__(256) void to_bf16(
    const float* __restrict__ src, __hip_bfloat16* __restrict__ dst, int n4)
{
    int i = blockIdx.x * blockDim.x + threadIdx.x;
    if (i < n4) {
        float4 v = *(const float4*)(src + (size_t)i * 4);
        dst[(size_t)i * 4 + 0] = __float2bfloat16(v.x);
        dst[(size_t)i * 4 + 1] = __float2bfloat16(v.y);
        dst[(size_t)i * 4 + 2] = __float2bfloat16(v.z);
        dst[(size_t)i * 4 + 3] = __float2bfloat16(v.w);
    }
}

// ---------------------------------------------------------------------------
// permute_w1: k = c*8+p -> k' = p*128+c, coalesced reads via LDS staging.
// ---------------------------------------------------------------------------
__global__ __launch_bounds__(256) void permute_w1(
    const float* __restrict__ w1, __hip_bfloat16* __restrict__ w1p)
{
    __shared__ float row[1024];
    const int n = blockIdx.x;
    const int t = threadIdx.x;
    ((float4*)row)[t] = ((const float4*)(w1 + (size_t)n * 1024))[t];
    __syncthreads();
    unsigned int* dst = (unsigned int*)(w1p + (size_t)n * 1024);
#pragma unroll
    for (int pass = 0; pass < 2; ++pass) {
        int j = pass * 256 + t;        // uint index; elements 2j, 2j+1
        int k0 = 2 * j, k1 = 2 * j + 1;
        float v0 = row[(k0 & 127) * 8 + (k0 >> 7)];
        float v1 = row[(k1 & 127) * 8 + (k1 >> 7)];
        union { __hip_bfloat16 h[2]; unsigned int u; } pk;
        pk.h[0] = __float2bfloat16(v0);
        pk.h[1] = __float2bfloat16(v1);
        dst[j] = pk.u;
    }
}

// ---------------------------------------------------------------------------
// MFMA bf16 GEMM, BK=64, 32x32x16 engine.
// 128x128 tile, 4 waves 2x2 (wave tile 64x64 = 2x2 blocks of 32x32).
// Staging identical to the proven BK=64 layout: 2 panels of [128 rows][32 k],
// filled by 4 x global_load_lds(16B) rounds.
// Fragments (32x32x16): A row m = lane&31, k = (lane>>5)*8 + i  -> one b128
// per block per 16-k step; 2x fewer LDS reads per FLOP than 16x16x32.
// C/D: col = lane&31, row = (reg&3) + 8*(reg>>2) + 4*(lane>>5)  [m74/m101].
// XCD-aware swizzle: lid%8 = XCD, n fastest -> A-tile reused within one XCD.
// ---------------------------------------------------------------------------
__global__ __launch_bounds__(256) void mfma_gemm(
    const __hip_bfloat16* __restrict__ A,   // (M, K) row-major
    const __hip_bfloat16* __restrict__ B,   // (N, K) row-major (= B^T)
    const float* __restrict__ bias,         // (N)
    __hip_bfloat16* __restrict__ out,       // (M, N)
    int M, int N, int K, int n_tiles)
{
    __shared__ __hip_bfloat16 As[128 * 64];   // 16 KB
    __shared__ __hip_bfloat16 Bs[128 * 64];   // 16 KB
    const int tid  = threadIdx.x;
    const int lane = tid & 63;
    const int wave = tid >> 6;
    const int wr = wave >> 1, wc = wave & 1;    // 2x2 wave grid
    const int l32  = lane & 31;
    const int half = lane >> 5;                 // k-half selector

    // XCD-aware relabel (grid must be divisible by 8)
    const int lid = blockIdx.x;
    const int per = gridDim.x >> 3;
    const int g   = (lid & 7) * per + (lid >> 3);
    const int n0 = (g % n_tiles) * 128;
    const int m0 = (g / n_tiles) * 128;

    f32x16 acc[2][2];
#pragma unroll
    for (int i = 0; i < 2; ++i)
#pragma unroll
        for (int j = 0; j < 2; ++j)
#pragma unroll
            for (int r = 0; r < 16; ++r) acc[i][j][r] = 0.0f;

    for (int k0 = 0; k0 < K; k0 += 64) {
        // ---- stage A,B 128x64 tiles: 4 sites x 256 thr x 16 B each ----
#pragma unroll
        for (int s = 0; s < 4; ++s) {
            int li   = s * 256 + tid;          // chunk 0..1023
            int row  = (li & 511) >> 2;        // 0..127
            int ke   = (li >> 9) * 32 + (li & 3) * 8;  // k element offset 0..63
            const __hip_bfloat16* ga = A + (size_t)(m0 + row) * K + k0 + ke;
            const __hip_bfloat16* gb = B + (size_t)(n0 + row) * K + k0 + ke;
            int chunk = s * 256 + (tid & ~63); // wave-uniform base chunk
            __builtin_amdgcn_global_load_lds(
                (const __attribute__((address_space(1))) unsigned int*)ga,
                (__attribute__((address_space(3))) unsigned int*)(As + chunk * 8),
                16, 0, 0);
            __builtin_amdgcn_global_load_lds(
                (const __attribute__((address_space(1))) unsigned int*)gb,
                (__attribute__((address_space(3))) unsigned int*)(Bs + chunk * 8),
                16, 0, 0);
        }
        __syncthreads();

        // ---- 2 panels x 2 k-steps of 16: fragments + 32x32x16 MFMA ----
#pragma unroll
        for (int kh = 0; kh < 2; ++kh) {
            const short* ap = (const short*)As + kh * 4096;
            const short* bp = (const short*)Bs + kh * 4096;
#pragma unroll
            for (int ks = 0; ks < 2; ++ks) {
                int koff = ks * 16 + half * 8;
                short8 af[2], bf[2];
#pragma unroll
                for (int bm = 0; bm < 2; ++bm) {
                    int row = wr * 64 + bm * 32 + l32;
                    af[bm] = *(const short8*)(ap + row * 32 + koff);
                }
#pragma unroll
                for (int bn = 0; bn < 2; ++bn) {
                    int row = wc * 64 + bn * 32 + l32;
                    bf[bn] = *(const short8*)(bp + row * 32 + koff);
                }
#pragma unroll
                for (int bm = 0; bm < 2; ++bm)
#pragma unroll
                    for (int bn = 0; bn < 2; ++bn)
                        acc[bm][bn] = __builtin_amdgcn_mfma_f32_32x32x16_bf16(
                            af[bm], bf[bn], acc[bm][bn], 0, 0, 0);
            }
        }
        __syncthreads();
    }

    // ---- epilogue: C col = lane&31, row = (reg&3)+8*(reg>>2)+4*half ----
#pragma unroll
    for (int bn = 0; bn < 2; ++bn) {
        int n = n0 + wc * 64 + bn * 32 + l32;
        float bv = bias[n];
#pragma unroll
        for (int bm = 0; bm < 2; ++bm) {
            int mbase = m0 + wr * 64 + bm * 32 + half * 4;
#pragma unroll
            for (int r = 0; r < 16; ++r) {
                int m = mbase + (r & 3) + 8 * (r >> 2);
                float v = acc[bm][bn][r] + bv;
                v = v > 0.0f ? v : 0.0f;
                out[(size_t)m * N + n] = (__hip_bfloat16)v;
            }
        }
    }
}

// ---------------------------------------------------------------------------
// Head: one wave per line: logits[l][n] = sum_k x2[l][k]*w3[n][k] + b3[n]
// ---------------------------------------------------------------------------
__global__ __launch_bounds__(256) void head_kernel(
    const __hip_bfloat16* __restrict__ x2,  // (N_LINES, 1024) bf16
    const float* __restrict__ w3,           // (3, 1024)
    const float* __restrict__ b3,           // (3)
    float* __restrict__ out)                // (N_LINES, 3)
{
    const int gtid = blockIdx.x * blockDim.x + threadIdx.x;
    const int l = gtid >> 6;
    const int lane = threadIdx.x & 63;
    if (l >= N_LINES) return;
    const __hip_bfloat16* xr = x2 + (size_t)l * DIM_FC;
    float s0 = 0.0f, s1 = 0.0f, s2 = 0.0f;
#pragma unroll
    for (int it = 0; it < 4; ++it) {
        int k = it * 256 + lane * 4;
        ushort4 xv = *(const ushort4*)(xr + k);
        float x0 = __uint_as_float((unsigned)xv.x << 16);
        float x1 = __uint_as_float((unsigned)xv.y << 16);
        float x2v = __uint_as_float((unsigned)xv.z << 16);
        float x3 = __uint_as_float((unsigned)xv.w << 16);
        float4 wa = *(const float4*)(w3 + 0 * DIM_FC + k);
        float4 wb = *(const float4*)(w3 + 1 * DIM_FC + k);
        float4 wc = *(const float4*)(w3 + 2 * DIM_FC + k);
        s0 += x0 * wa.x + x1 * wa.y + x2v * wa.z + x3 * wa.w;
        s1 += x0 * wb.x + x1 * wb.y + x2v * wb.z + x3 * wb.w;
        s2 += x0 * wc.x + x1 * wc.y + x2v * wc.z + x3 * wc.w;
    }
#pragma unroll
    for (int off = 32; off > 0; off >>= 1) {
        s0 += __shfl_xor(s0, off);
        s1 += __shfl_xor(s1, off);
        s2 += __shfl_xor(s2, off);
    }
    if (lane == 0) {
        out[(size_t)l * 3 + 0] = s0 + b3[0];
        out[(size_t)l * 3 + 1] = s1 + b3[1];
        out[(size_t)l * 3 + 2] = s2 + b3[2];
    }
}

// ---------------------------------------------------------------------------
extern "C" void kernel_launch(void* const* d_in, const int* in_sizes, int n_in,
                              void* d_out, int out_size, void* d_ws, size_t ws_size,
                              hipStream_t stream) {
    const float* features = (const float*)d_in[0];  // (1,256,128,128)
    const float* lines    = (const float*)d_in[1];  // (16000,4)
    const float* w_fc1    = (const float*)d_in[2];  // (128,256)
    const float* b_fc1    = (const float*)d_in[3];  // (128)
    const float* w1       = (const float*)d_in[4];  // (1024,1024)
    const float* b1       = (const float*)d_in[5];  // (1024)
    const float* w2       = (const float*)d_in[6];  // (1024,1024)
    const float* b2       = (const float*)d_in[7];  // (1024)
    const float* w3       = (const float*)d_in[8];  // (3,1024)
    const float* b3       = (const float*)d_in[9];  // (3)
    float* out = (float*)d_out;

    char* ws = (char*)d_ws;
    __hip_bfloat16* loi    = (__hip_bfloat16*)ws;
    __hip_bfloat16* featb  = (__hip_bfloat16*)(ws + (size_t)8 * 1024 * 1024);
    __hip_bfloat16* x1b    = (__hip_bfloat16*)(ws + (size_t)40 * 1024 * 1024);
    __hip_bfloat16* x2b    = featb;   // reuse (featb dead after GEMM1)
    __hip_bfloat16* w1b    = (__hip_bfloat16*)(ws + (size_t)72 * 1024 * 1024);
    __hip_bfloat16* w2b    = (__hip_bfloat16*)(ws + (size_t)74 * 1024 * 1024);
    __hip_bfloat16* featsT = (__hip_bfloat16*)(ws + (size_t)76 * 1024 * 1024);
    __hip_bfloat16* wfc1b  = (__hip_bfloat16*)(ws + (size_t)84 * 1024 * 1024);

    // 0) precision conversions / permutations
    transpose_feats<<<dim3(NPIX / 64, C_IN / 64), 256, 0, stream>>>(features, featsT);
    to_bf16<<<dim3((DIM_LOI * C_IN / 4 + 255) / 256), 256, 0, stream>>>(w_fc1, wfc1b, DIM_LOI * C_IN / 4);
    permute_w1<<<dim3(DIM_FC), 256, 0, stream>>>(w1, w1b);
    to_bf16<<<dim3((DIM_FC * DIM_FC / 4 + 255) / 256), 256, 0, stream>>>(w2, w2b, DIM_FC * DIM_FC / 4);

    // 1) conv1x1 as MFMA GEMM (grid 128, 1 n-tile, K=256 -> 4 iters)
    mfma_gemm<<<dim3(NPIX / 128), 256, 0, stream>>>(
        featsT, wfc1b, b_fc1, loi, NPIX, DIM_LOI, C_IN, 1);

    // 2) line pooling -> featb (16000,1024) bf16, k' = p*128+c
    pool_kernel<<<dim3(N_LINES / 4), 256, 0, stream>>>(loi, lines, featb);

    // 3) x1 = relu(feat @ w1p^T + b1)   grid 1000 = 125 m x 8 n
    mfma_gemm<<<dim3((N_LINES / 128) * (DIM_FC / 128)), 256, 0, stream>>>(
        featb, w1b, b1, x1b, N_LINES, DIM_FC, DIM_FC, DIM_FC / 128);

    // 4) x2 = relu(x1 @ w2^T + b2)
    mfma_gemm<<<dim3((N_LINES / 128) * (DIM_FC / 128)), 256, 0, stream>>>(
        x1b, w2b, b2, x2b, N_LINES, DIM_FC, DIM_FC, DIM_FC / 128);

    // 5) logits = x2 @ w3^T + b3
    head_kernel<<<dim3((N_LINES * 64 + 255) / 256), 256, 0, stream>>>(x2b, w3, b3, out);
}

// Round 10
// 230.080 us; speedup vs baseline: 1.1842x; 1.0570x over previous
//
#include <hip/hip_runtime.h>
#include <hip/hip_bf16.h>
#include <math.h>

// Problem dims (fixed)
#define C_IN 256
#define HW 128          // H = W = 128
#define NPIX (HW*HW)    // 16384
#define DIM_LOI 128
#define N_LINES 16000
#define N_PTS0 32
#define N_PTS1 8
#define DIM_FC 1024
#define N_LABELS 3

typedef __attribute__((ext_vector_type(8))) short short8;   // 8 bf16 = 4 VGPRs
typedef __attribute__((ext_vector_type(4))) float f32x4;

// ---------------------------------------------------------------------------
// prep_kernel: all input conversions in ONE dispatch (branch on blockIdx).
//  [0,1024)    : transpose+bf16 features (256,16384) -> featsT (16384,256)
//  [1024,2048) : permute_w1  k=c*8+p -> k'=p*128+c, fp32->bf16
//  [2048,3072) : to_bf16 w2
//  [3072,3104) : to_bf16 w_fc1
// ---------------------------------------------------------------------------
__global__ __launch_bounds__(256) void prep_kernel(
    const float* __restrict__ feats, __hip_bfloat16* __restrict__ featsT,
    const float* __restrict__ w1,    __hip_bfloat16* __restrict__ w1p,
    const float* __restrict__ w2,    __hip_bfloat16* __restrict__ w2b,
    const float* __restrict__ wfc1,  __hip_bfloat16* __restrict__ wfc1b)
{
    __shared__ float tile[64][65];
    const int b = blockIdx.x;
    const int t = threadIdx.x;

    if (b < 1024) {
        // ---- transpose features ----
        const int p0 = (b & 255) * 64;
        const int c0 = (b >> 8) * 64;
#pragma unroll
        for (int i = 0; i < 4; ++i) {
            int c = (t >> 4) + i * 16;
            int p4 = (t & 15) * 4;
            float4 v = *(const float4*)(feats + (size_t)(c0 + c) * NPIX + p0 + p4);
            tile[c][p4 + 0] = v.x;
            tile[c][p4 + 1] = v.y;
            tile[c][p4 + 2] = v.z;
            tile[c][p4 + 3] = v.w;
        }
        __syncthreads();
#pragma unroll
        for (int i = 0; i < 2; ++i) {
            int p = (t >> 3) + i * 32;
            int cc = (t & 7) * 8;
            union { __hip_bfloat16 h[8]; uint4 u4; } pk;
#pragma unroll
            for (int j = 0; j < 8; ++j) pk.h[j] = __float2bfloat16(tile[cc + j][p]);
            *(uint4*)(featsT + (size_t)(p0 + p) * C_IN + c0 + cc) = pk.u4;
        }
    } else if (b < 2048) {
        // ---- permute w1 row ----
        float* row = &tile[0][0];
        const int n = b - 1024;
        ((float4*)row)[t] = ((const float4*)(w1 + (size_t)n * 1024))[t];
        __syncthreads();
        unsigned int* dst = (unsigned int*)(w1p + (size_t)n * 1024);
#pragma unroll
        for (int pass = 0; pass < 2; ++pass) {
            int j = pass * 256 + t;
            int k0 = 2 * j, k1 = 2 * j + 1;
            float v0 = row[(k0 & 127) * 8 + (k0 >> 7)];
            float v1 = row[(k1 & 127) * 8 + (k1 >> 7)];
            union { __hip_bfloat16 h[2]; unsigned int u; } pk;
            pk.h[0] = __float2bfloat16(v0);
            pk.h[1] = __float2bfloat16(v1);
            dst[j] = pk.u;
        }
    } else if (b < 3072) {
        int i = (b - 2048) * 256 + t;     // float4 index into w2
        float4 v = *(const float4*)(w2 + (size_t)i * 4);
        union { __hip_bfloat16 h[4]; uint2 u; } pk;
        pk.h[0] = __float2bfloat16(v.x);
        pk.h[1] = __float2bfloat16(v.y);
        pk.h[2] = __float2bfloat16(v.z);
        pk.h[3] = __float2bfloat16(v.w);
        *(uint2*)(w2b + (size_t)i * 4) = pk.u;
    } else {
        int i = (b - 3072) * 256 + t;     // float4 index into w_fc1 (8192 total)
        float4 v = *(const float4*)(wfc1 + (size_t)i * 4);
        union { __hip_bfloat16 h[4]; uint2 u; } pk;
        pk.h[0] = __float2bfloat16(v.x);
        pk.h[1] = __float2bfloat16(v.y);
        pk.h[2] = __float2bfloat16(v.z);
        pk.h[3] = __float2bfloat16(v.w);
        *(uint2*)(wfc1b + (size_t)i * 4) = pk.u;
    }
}

// ---------------------------------------------------------------------------
// Line pool v2. 256 thr = 4 lines x 1 wave; wave = 2 half-waves of 32 lanes:
// half h handles points 4h..4h+3; lane t owns channels 4t..4t+3 (uint2
// gathers -> half the vmem instructions of the uint version, same bytes).
// feat layout k' = p*128 + c (matches permuted w1).
// ---------------------------------------------------------------------------
__global__ __launch_bounds__(256) void pool_kernel(
    const __hip_bfloat16* __restrict__ loi,   // (NPIX, 128) bf16 channel-last
    const float* __restrict__ lines,          // (N_LINES, 4)
    __hip_bfloat16* __restrict__ feat)        // (N_LINES, 1024), k' = p*128+c
{
    __shared__ int   offs[4][N_PTS0][4];      // uint2-index base (pix*32)
    __shared__ float wts[4][N_PTS0][4];
    const int g    = threadIdx.x >> 6;   // line group in block
    const int lane = threadIdx.x & 63;
    const int h    = lane >> 5;          // point-half selector
    const int t    = lane & 31;          // channel group: 4t..4t+3
    const int l    = blockIdx.x * 4 + g;

    if (lane < N_PTS0) {
        int j = lane;
        float tt = (float)j * (1.0f / 31.0f);
        float U0 = lines[4 * l + 0], U1 = lines[4 * l + 1];
        float V0 = lines[4 * l + 2], V1 = lines[4 * l + 3];
        float px = U0 * tt + V0 * (1.0f - tt) - 0.5f;
        float py = U1 * tt + V1 * (1.0f - tt) - 0.5f;
        float px0 = fminf(fmaxf(floorf(px), 0.0f), 127.0f);
        float py0 = fminf(fmaxf(floorf(py), 0.0f), 127.0f);
        float px1 = fminf(fmaxf(px0 + 1.0f, 0.0f), 127.0f);
        float py1 = fminf(fmaxf(py0 + 1.0f, 0.0f), 127.0f);
        int ix0 = (int)px0, iy0 = (int)py0, ix1 = (int)px1, iy1 = (int)py1;
        float wx0 = px1 - px, wx1 = px - px0;
        float wy0 = py1 - py, wy1 = py - py0;
        offs[g][j][0] = (iy0 * HW + ix0) * 32;
        offs[g][j][1] = (iy1 * HW + ix0) * 32;
        offs[g][j][2] = (iy0 * HW + ix1) * 32;
        offs[g][j][3] = (iy1 * HW + ix1) * 32;
        wts[g][j][0] = wy0 * wx0;
        wts[g][j][1] = wy1 * wx0;
        wts[g][j][2] = wy0 * wx1;
        wts[g][j][3] = wy1 * wx1;
    }
    __syncthreads();

    const uint2* loi2 = (const uint2*)loi;
    uint2* featw = (uint2*)(feat + (size_t)l * (N_PTS1 * DIM_LOI));

#pragma unroll
    for (int p = 0; p < 4; ++p) {
        const int point = h * 4 + p;
        float b0 = -INFINITY, b1 = -INFINITY, b2 = -INFINITY, b3 = -INFINITY;
#pragma unroll
        for (int q = 0; q < 4; ++q) {
            int j = point * 4 + q;
            uint2 v0 = loi2[offs[g][j][0] + t];
            uint2 v1 = loi2[offs[g][j][1] + t];
            uint2 v2 = loi2[offs[g][j][2] + t];
            uint2 v3 = loi2[offs[g][j][3] + t];
            float w0 = wts[g][j][0], w1 = wts[g][j][1];
            float w2 = wts[g][j][2], w3 = wts[g][j][3];
            float s0 = w0 * __uint_as_float(v0.x << 16)
                     + w1 * __uint_as_float(v1.x << 16)
                     + w2 * __uint_as_float(v2.x << 16)
                     + w3 * __uint_as_float(v3.x << 16);
            float s1 = w0 * __uint_as_float(v0.x & 0xffff0000u)
                     + w1 * __uint_as_float(v1.x & 0xffff0000u)
                     + w2 * __uint_as_float(v2.x & 0xffff0000u)
                     + w3 * __uint_as_float(v3.x & 0xffff0000u);
            float s2 = w0 * __uint_as_float(v0.y << 16)
                     + w1 * __uint_as_float(v1.y << 16)
                     + w2 * __uint_as_float(v2.y << 16)
                     + w3 * __uint_as_float(v3.y << 16);
            float s3 = w0 * __uint_as_float(v0.y & 0xffff0000u)
                     + w1 * __uint_as_float(v1.y & 0xffff0000u)
                     + w2 * __uint_as_float(v2.y & 0xffff0000u)
                     + w3 * __uint_as_float(v3.y & 0xffff0000u);
            b0 = fmaxf(b0, s0);
            b1 = fmaxf(b1, s1);
            b2 = fmaxf(b2, s2);
            b3 = fmaxf(b3, s3);
        }
        union { __hip_bfloat16 hh[4]; uint2 u; } pk;
        pk.hh[0] = __float2bfloat16(b0);
        pk.hh[1] = __float2bfloat16(b1);
        pk.hh[2] = __float2bfloat16(b2);
        pk.hh[3] = __float2bfloat16(b3);
        featw[point * 32 + t] = pk.u;    // element point*128 + 4t
    }
}

// ---------------------------------------------------------------------------
// MFMA bf16 GEMM, BK=64 (R6-exact core — best known, replay-stable).
// 128x128 tile, 4 waves 2x2, each wave 4x4 of 16x16x32 MFMA.
// XCD-aware swizzle: lid%8 = XCD, n fastest -> A-tile reused within one XCD.
// ---------------------------------------------------------------------------
__global__ __launch_bounds__(256) void mfma_gemm(
    const __hip_bfloat16* __restrict__ A,   // (M, K) row-major
    const __hip_bfloat16* __restrict__ B,   // (N, K) row-major (= B^T)
    const float* __restrict__ bias,         // (N)
    __hip_bfloat16* __restrict__ out,       // (M, N)
    int M, int N, int K, int n_tiles)
{
    __shared__ __hip_bfloat16 As[128 * 64];   // 16 KB
    __shared__ __hip_bfloat16 Bs[128 * 64];   // 16 KB
    const int tid  = threadIdx.x;
    const int lane = tid & 63;
    const int wave = tid >> 6;
    const int wr = wave >> 1, wc = wave & 1;    // 2x2 wave grid
    const int quad = lane >> 4;
    const int l16  = lane & 15;

    // XCD-aware relabel (grid must be divisible by 8)
    const int lid = blockIdx.x;
    const int per = gridDim.x >> 3;
    const int g   = (lid & 7) * per + (lid >> 3);
    const int n0 = (g % n_tiles) * 128;
    const int m0 = (g / n_tiles) * 128;

    f32x4 acc[4][4];
#pragma unroll
    for (int i = 0; i < 4; ++i)
#pragma unroll
        for (int j = 0; j < 4; ++j) { f32x4 z = {0.f, 0.f, 0.f, 0.f}; acc[i][j] = z; }

    for (int k0 = 0; k0 < K; k0 += 64) {
        // ---- stage A,B 128x64 tiles: 4 sites x 256 thr x 16 B each ----
#pragma unroll
        for (int s = 0; s < 4; ++s) {
            int li   = s * 256 + tid;          // chunk 0..1023
            int row  = (li & 511) >> 2;        // 0..127
            int ke   = (li >> 9) * 32 + (li & 3) * 8;  // k element offset 0..63
            const __hip_bfloat16* ga = A + (size_t)(m0 + row) * K + k0 + ke;
            const __hip_bfloat16* gb = B + (size_t)(n0 + row) * K + k0 + ke;
            int chunk = s * 256 + (tid & ~63); // wave-uniform base chunk
            __builtin_amdgcn_global_load_lds(
                (const __attribute__((address_space(1))) unsigned int*)ga,
                (__attribute__((address_space(3))) unsigned int*)(As + chunk * 8),
                16, 0, 0);
            __builtin_amdgcn_global_load_lds(
                (const __attribute__((address_space(1))) unsigned int*)gb,
                (__attribute__((address_space(3))) unsigned int*)(Bs + chunk * 8),
                16, 0, 0);
        }
        __syncthreads();

        // ---- two 32-k halves: fragments + MFMA ----
#pragma unroll
        for (int kh = 0; kh < 2; ++kh) {
            const short* ap = (const short*)As + kh * 4096;
            const short* bp = (const short*)Bs + kh * 4096;
            short8 af[4], bf[4];
#pragma unroll
            for (int mt = 0; mt < 4; ++mt) {
                int row = wr * 64 + mt * 16 + l16;
                af[mt] = *(const short8*)(ap + row * 32 + quad * 8);
            }
#pragma unroll
            for (int nt = 0; nt < 4; ++nt) {
                int row = wc * 64 + nt * 16 + l16;
                bf[nt] = *(const short8*)(bp + row * 32 + quad * 8);
            }
#pragma unroll
            for (int mt = 0; mt < 4; ++mt)
#pragma unroll
                for (int nt = 0; nt < 4; ++nt)
                    acc[mt][nt] = __builtin_amdgcn_mfma_f32_16x16x32_bf16(
                        af[mt], bf[nt], acc[mt][nt], 0, 0, 0);
        }
        __syncthreads();
    }

    // ---- epilogue: C row = quad*4 + r, col = l16 ----
#pragma unroll
    for (int nt = 0; nt < 4; ++nt) {
        int n = n0 + wc * 64 + nt * 16 + l16;
        float bv = bias[n];
#pragma unroll
        for (int mt = 0; mt < 4; ++mt) {
            int mbase = m0 + wr * 64 + mt * 16 + quad * 4;
#pragma unroll
            for (int r = 0; r < 4; ++r) {
                float v = acc[mt][nt][r] + bv;
                v = v > 0.0f ? v : 0.0f;
                out[(size_t)(mbase + r) * N + n] = (__hip_bfloat16)v;
            }
        }
    }
}

// ---------------------------------------------------------------------------
// Head: one wave per line: logits[l][n] = sum_k x2[l][k]*w3[n][k] + b3[n]
// ---------------------------------------------------------------------------
__global__ __launch_bounds__(256) void head_kernel(
    const __hip_bfloat16* __restrict__ x2,  // (N_LINES, 1024) bf16
    const float* __restrict__ w3,           // (3, 1024)
    const float* __restrict__ b3,           // (3)
    float* __restrict__ out)                // (N_LINES, 3)
{
    const int gtid = blockIdx.x * blockDim.x + threadIdx.x;
    const int l = gtid >> 6;
    const int lane = threadIdx.x & 63;
    if (l >= N_LINES) return;
    const __hip_bfloat16* xr = x2 + (size_t)l * DIM_FC;
    float s0 = 0.0f, s1 = 0.0f, s2 = 0.0f;
#pragma unroll
    for (int it = 0; it < 4; ++it) {
        int k = it * 256 + lane * 4;
        ushort4 xv = *(const ushort4*)(xr + k);
        float x0 = __uint_as_float((unsigned)xv.x << 16);
        float x1 = __uint_as_float((unsigned)xv.y << 16);
        float x2v = __uint_as_float((unsigned)xv.z << 16);
        float x3 = __uint_as_float((unsigned)xv.w << 16);
        float4 wa = *(const float4*)(w3 + 0 * DIM_FC + k);
        float4 wb = *(const float4*)(w3 + 1 * DIM_FC + k);
        float4 wc = *(const float4*)(w3 + 2 * DIM_FC + k);
        s0 += x0 * wa.x + x1 * wa.y + x2v * wa.z + x3 * wa.w;
        s1 += x0 * wb.x + x1 * wb.y + x2v * wb.z + x3 * wb.w;
        s2 += x0 * wc.x + x1 * wc.y + x2v * wc.z + x3 * wc.w;
    }
#pragma unroll
    for (int off = 32; off > 0; off >>= 1) {
        s0 += __shfl_xor(s0, off);
        s1 += __shfl_xor(s1, off);
        s2 += __shfl_xor(s2, off);
    }
    if (lane == 0) {
        out[(size_t)l * 3 + 0] = s0 + b3[0];
        out[(size_t)l * 3 + 1] = s1 + b3[1];
        out[(size_t)l * 3 + 2] = s2 + b3[2];
    }
}

// ---------------------------------------------------------------------------
extern "C" void kernel_launch(void* const* d_in, const int* in_sizes, int n_in,
                              void* d_out, int out_size, void* d_ws, size_t ws_size,
                              hipStream_t stream) {
    const float* features = (const float*)d_in[0];  // (1,256,128,128)
    const float* lines    = (const float*)d_in[1];  // (16000,4)
    const float* w_fc1    = (const float*)d_in[2];  // (128,256)
    const float* b_fc1    = (const float*)d_in[3];  // (128)
    const float* w1       = (const float*)d_in[4];  // (1024,1024)
    const float* b1       = (const float*)d_in[5];  // (1024)
    const float* w2       = (const float*)d_in[6];  // (1024,1024)
    const float* b2       = (const float*)d_in[7];  // (1024)
    const float* w3       = (const float*)d_in[8];  // (3,1024)
    const float* b3       = (const float*)d_in[9];  // (3)
    float* out = (float*)d_out;

    char* ws = (char*)d_ws;
    __hip_bfloat16* loi    = (__hip_bfloat16*)ws;
    __hip_bfloat16* featb  = (__hip_bfloat16*)(ws + (size_t)8 * 1024 * 1024);
    __hip_bfloat16* x1b    = (__hip_bfloat16*)(ws + (size_t)40 * 1024 * 1024);
    __hip_bfloat16* x2b    = featb;   // reuse (featb dead after GEMM1)
    __hip_bfloat16* w1b    = (__hip_bfloat16*)(ws + (size_t)72 * 1024 * 1024);
    __hip_bfloat16* w2b    = (__hip_bfloat16*)(ws + (size_t)74 * 1024 * 1024);
    __hip_bfloat16* featsT = (__hip_bfloat16*)(ws + (size_t)76 * 1024 * 1024);
    __hip_bfloat16* wfc1b  = (__hip_bfloat16*)(ws + (size_t)84 * 1024 * 1024);

    // 0) all prep in one dispatch
    prep_kernel<<<dim3(3104), 256, 0, stream>>>(
        features, featsT, w1, w1b, w2, w2b, w_fc1, wfc1b);

    // 1) conv1x1 as MFMA GEMM (grid 128, 1 n-tile, K=256 -> 4 iters)
    mfma_gemm<<<dim3(NPIX / 128), 256, 0, stream>>>(
        featsT, wfc1b, b_fc1, loi, NPIX, DIM_LOI, C_IN, 1);

    // 2) line pooling -> featb (16000,1024) bf16, k' = p*128+c
    pool_kernel<<<dim3(N_LINES / 4), 256, 0, stream>>>(loi, lines, featb);

    // 3) x1 = relu(feat @ w1p^T + b1)   grid 1000 = 125 m x 8 n
    mfma_gemm<<<dim3((N_LINES / 128) * (DIM_FC / 128)), 256, 0, stream>>>(
        featb, w1b, b1, x1b, N_LINES, DIM_FC, DIM_FC, DIM_FC / 128);

    // 4) x2 = relu(x1 @ w2^T + b2)
    mfma_gemm<<<dim3((N_LINES / 128) * (DIM_FC / 128)), 256, 0, stream>>>(
        x1b, w2b, b2, x2b, N_LINES, DIM_FC, DIM_FC, DIM_FC / 128);

    // 5) logits = x2 @ w3^T + b3
    head_kernel<<<dim3((N_LINES * 64 + 255) / 256), 256, 0, stream>>>(x2b, w3, b3, out);
}

// Round 11
// 220.255 us; speedup vs baseline: 1.2370x; 1.0446x over previous
//
#include <hip/hip_runtime.h>
#include <hip/hip_bf16.h>
#include <math.h>

// Problem dims (fixed)
#define C_IN 256
#define HW 128          // H = W = 128
#define NPIX (HW*HW)    // 16384
#define DIM_LOI 128
#define N_LINES 16000
#define N_PTS0 32
#define N_PTS1 8
#define DIM_FC 1024
#define N_LABELS 3

typedef __attribute__((ext_vector_type(8))) short short8;   // 8 bf16 = 4 VGPRs
typedef __attribute__((ext_vector_type(4))) float f32x4;

// ---------------------------------------------------------------------------
// prep_kernel: all input conversions in ONE dispatch (branch on blockIdx).
//  [0,1024)    : transpose+bf16 features (256,16384) -> featsT (16384,256)
//  [1024,2048) : permute_w1  k=c*8+p -> k'=p*128+c, fp32->bf16
//  [2048,3072) : to_bf16 w2
//  [3072,3104) : to_bf16 w_fc1
// ---------------------------------------------------------------------------
__global__ __launch_bounds__(256) void prep_kernel(
    const float* __restrict__ feats, __hip_bfloat16* __restrict__ featsT,
    const float* __restrict__ w1,    __hip_bfloat16* __restrict__ w1p,
    const float* __restrict__ w2,    __hip_bfloat16* __restrict__ w2b,
    const float* __restrict__ wfc1,  __hip_bfloat16* __restrict__ wfc1b)
{
    __shared__ float tile[64][65];
    const int b = blockIdx.x;
    const int t = threadIdx.x;

    if (b < 1024) {
        // ---- transpose features ----
        const int p0 = (b & 255) * 64;
        const int c0 = (b >> 8) * 64;
#pragma unroll
        for (int i = 0; i < 4; ++i) {
            int c = (t >> 4) + i * 16;
            int p4 = (t & 15) * 4;
            float4 v = *(const float4*)(feats + (size_t)(c0 + c) * NPIX + p0 + p4);
            tile[c][p4 + 0] = v.x;
            tile[c][p4 + 1] = v.y;
            tile[c][p4 + 2] = v.z;
            tile[c][p4 + 3] = v.w;
        }
        __syncthreads();
#pragma unroll
        for (int i = 0; i < 2; ++i) {
            int p = (t >> 3) + i * 32;
            int cc = (t & 7) * 8;
            union { __hip_bfloat16 h[8]; uint4 u4; } pk;
#pragma unroll
            for (int j = 0; j < 8; ++j) pk.h[j] = __float2bfloat16(tile[cc + j][p]);
            *(uint4*)(featsT + (size_t)(p0 + p) * C_IN + c0 + cc) = pk.u4;
        }
    } else if (b < 2048) {
        // ---- permute w1 row ----
        float* row = &tile[0][0];
        const int n = b - 1024;
        ((float4*)row)[t] = ((const float4*)(w1 + (size_t)n * 1024))[t];
        __syncthreads();
        unsigned int* dst = (unsigned int*)(w1p + (size_t)n * 1024);
#pragma unroll
        for (int pass = 0; pass < 2; ++pass) {
            int j = pass * 256 + t;
            int k0 = 2 * j, k1 = 2 * j + 1;
            float v0 = row[(k0 & 127) * 8 + (k0 >> 7)];
            float v1 = row[(k1 & 127) * 8 + (k1 >> 7)];
            union { __hip_bfloat16 h[2]; unsigned int u; } pk;
            pk.h[0] = __float2bfloat16(v0);
            pk.h[1] = __float2bfloat16(v1);
            dst[j] = pk.u;
        }
    } else if (b < 3072) {
        int i = (b - 2048) * 256 + t;     // float4 index into w2
        float4 v = *(const float4*)(w2 + (size_t)i * 4);
        union { __hip_bfloat16 h[4]; uint2 u; } pk;
        pk.h[0] = __float2bfloat16(v.x);
        pk.h[1] = __float2bfloat16(v.y);
        pk.h[2] = __float2bfloat16(v.z);
        pk.h[3] = __float2bfloat16(v.w);
        *(uint2*)(w2b + (size_t)i * 4) = pk.u;
    } else {
        int i = (b - 3072) * 256 + t;     // float4 index into w_fc1 (8192 total)
        float4 v = *(const float4*)(wfc1 + (size_t)i * 4);
        union { __hip_bfloat16 h[4]; uint2 u; } pk;
        pk.h[0] = __float2bfloat16(v.x);
        pk.h[1] = __float2bfloat16(v.y);
        pk.h[2] = __float2bfloat16(v.z);
        pk.h[3] = __float2bfloat16(v.w);
        *(uint2*)(wfc1b + (size_t)i * 4) = pk.u;
    }
}

// ---------------------------------------------------------------------------
// Line pool v3. 256 thr = 4 lines x 1 wave; wave = 4 quarter-waves of 16:
// quarter qd handles output points {qd, qd+4}; lane t16 owns channels
// 8*t16..8*t16+7 via uint4 gathers (one 256-B corner row per 16 lanes).
// 32 vmem instructions per line (v2 had 64), 1 KB per instruction.
// feat layout k' = p*128 + c (matches permuted w1).
// ---------------------------------------------------------------------------
__global__ __launch_bounds__(256) void pool_kernel(
    const __hip_bfloat16* __restrict__ loi,   // (NPIX, 128) bf16 channel-last
    const float* __restrict__ lines,          // (N_LINES, 4)
    __hip_bfloat16* __restrict__ feat)        // (N_LINES, 1024), k' = p*128+c
{
    __shared__ int   offs[4][N_PTS0][4];      // uint4-index base (pix*16)
    __shared__ float wts[4][N_PTS0][4];
    const int g    = threadIdx.x >> 6;   // line group in block
    const int lane = threadIdx.x & 63;
    const int qd   = lane >> 4;          // quarter: output points qd, qd+4
    const int t16  = lane & 15;          // channel group 8*t16..8*t16+7
    const int l    = blockIdx.x * 4 + g;

    if (lane < N_PTS0) {
        int j = lane;
        float tt = (float)j * (1.0f / 31.0f);
        float U0 = lines[4 * l + 0], U1 = lines[4 * l + 1];
        float V0 = lines[4 * l + 2], V1 = lines[4 * l + 3];
        float px = U0 * tt + V0 * (1.0f - tt) - 0.5f;
        float py = U1 * tt + V1 * (1.0f - tt) - 0.5f;
        float px0 = fminf(fmaxf(floorf(px), 0.0f), 127.0f);
        float py0 = fminf(fmaxf(floorf(py), 0.0f), 127.0f);
        float px1 = fminf(fmaxf(px0 + 1.0f, 0.0f), 127.0f);
        float py1 = fminf(fmaxf(py0 + 1.0f, 0.0f), 127.0f);
        int ix0 = (int)px0, iy0 = (int)py0, ix1 = (int)px1, iy1 = (int)py1;
        float wx0 = px1 - px, wx1 = px - px0;
        float wy0 = py1 - py, wy1 = py - py0;
        offs[g][j][0] = (iy0 * HW + ix0) * 16;
        offs[g][j][1] = (iy1 * HW + ix0) * 16;
        offs[g][j][2] = (iy0 * HW + ix1) * 16;
        offs[g][j][3] = (iy1 * HW + ix1) * 16;
        wts[g][j][0] = wy0 * wx0;
        wts[g][j][1] = wy1 * wx0;
        wts[g][j][2] = wy0 * wx1;
        wts[g][j][3] = wy1 * wx1;
    }
    __syncthreads();

    const uint4* loi4 = (const uint4*)loi;
    uint4* featw = (uint4*)(feat + (size_t)l * (N_PTS1 * DIM_LOI));

#pragma unroll
    for (int p = 0; p < 2; ++p) {
        const int point = qd + 4 * p;   // 0..7
        float b0 = -INFINITY, b1 = -INFINITY, b2 = -INFINITY, b3 = -INFINITY;
        float b4 = -INFINITY, b5 = -INFINITY, b6 = -INFINITY, b7 = -INFINITY;
#pragma unroll
        for (int q = 0; q < 4; ++q) {
            int j = point * 4 + q;
            uint4 v0 = loi4[offs[g][j][0] + t16];
            uint4 v1 = loi4[offs[g][j][1] + t16];
            uint4 v2 = loi4[offs[g][j][2] + t16];
            uint4 v3 = loi4[offs[g][j][3] + t16];
            float w0 = wts[g][j][0], w1 = wts[g][j][1];
            float w2 = wts[g][j][2], w3 = wts[g][j][3];
            float s;
            s = w0 * __uint_as_float(v0.x << 16) + w1 * __uint_as_float(v1.x << 16)
              + w2 * __uint_as_float(v2.x << 16) + w3 * __uint_as_float(v3.x << 16);
            b0 = fmaxf(b0, s);
            s = w0 * __uint_as_float(v0.x & 0xffff0000u) + w1 * __uint_as_float(v1.x & 0xffff0000u)
              + w2 * __uint_as_float(v2.x & 0xffff0000u) + w3 * __uint_as_float(v3.x & 0xffff0000u);
            b1 = fmaxf(b1, s);
            s = w0 * __uint_as_float(v0.y << 16) + w1 * __uint_as_float(v1.y << 16)
              + w2 * __uint_as_float(v2.y << 16) + w3 * __uint_as_float(v3.y << 16);
            b2 = fmaxf(b2, s);
            s = w0 * __uint_as_float(v0.y & 0xffff0000u) + w1 * __uint_as_float(v1.y & 0xffff0000u)
              + w2 * __uint_as_float(v2.y & 0xffff0000u) + w3 * __uint_as_float(v3.y & 0xffff0000u);
            b3 = fmaxf(b3, s);
            s = w0 * __uint_as_float(v0.z << 16) + w1 * __uint_as_float(v1.z << 16)
              + w2 * __uint_as_float(v2.z << 16) + w3 * __uint_as_float(v3.z << 16);
            b4 = fmaxf(b4, s);
            s = w0 * __uint_as_float(v0.z & 0xffff0000u) + w1 * __uint_as_float(v1.z & 0xffff0000u)
              + w2 * __uint_as_float(v2.z & 0xffff0000u) + w3 * __uint_as_float(v3.z & 0xffff0000u);
            b5 = fmaxf(b5, s);
            s = w0 * __uint_as_float(v0.w << 16) + w1 * __uint_as_float(v1.w << 16)
              + w2 * __uint_as_float(v2.w << 16) + w3 * __uint_as_float(v3.w << 16);
            b6 = fmaxf(b6, s);
            s = w0 * __uint_as_float(v0.w & 0xffff0000u) + w1 * __uint_as_float(v1.w & 0xffff0000u)
              + w2 * __uint_as_float(v2.w & 0xffff0000u) + w3 * __uint_as_float(v3.w & 0xffff0000u);
            b7 = fmaxf(b7, s);
        }
        union { __hip_bfloat16 hh[8]; uint4 u; } pk;
        pk.hh[0] = __float2bfloat16(b0);
        pk.hh[1] = __float2bfloat16(b1);
        pk.hh[2] = __float2bfloat16(b2);
        pk.hh[3] = __float2bfloat16(b3);
        pk.hh[4] = __float2bfloat16(b4);
        pk.hh[5] = __float2bfloat16(b5);
        pk.hh[6] = __float2bfloat16(b6);
        pk.hh[7] = __float2bfloat16(b7);
        featw[point * 16 + t16] = pk.u;   // elements point*128 + 8*t16 ..+7
    }
}

// ---------------------------------------------------------------------------
// MFMA bf16 GEMM, BK=64 (R6-exact core — best known, replay-stable).
// 128x128 tile, 4 waves 2x2, each wave 4x4 of 16x16x32 MFMA.
// XCD-aware swizzle: lid%8 = XCD, n fastest -> A-tile reused within one XCD.
// ---------------------------------------------------------------------------
__global__ __launch_bounds__(256) void mfma_gemm(
    const __hip_bfloat16* __restrict__ A,   // (M, K) row-major
    const __hip_bfloat16* __restrict__ B,   // (N, K) row-major (= B^T)
    const float* __restrict__ bias,         // (N)
    __hip_bfloat16* __restrict__ out,       // (M, N)
    int M, int N, int K, int n_tiles)
{
    __shared__ __hip_bfloat16 As[128 * 64];   // 16 KB
    __shared__ __hip_bfloat16 Bs[128 * 64];   // 16 KB
    const int tid  = threadIdx.x;
    const int lane = tid & 63;
    const int wave = tid >> 6;
    const int wr = wave >> 1, wc = wave & 1;    // 2x2 wave grid
    const int quad = lane >> 4;
    const int l16  = lane & 15;

    // XCD-aware relabel (grid must be divisible by 8)
    const int lid = blockIdx.x;
    const int per = gridDim.x >> 3;
    const int g   = (lid & 7) * per + (lid >> 3);
    const int n0 = (g % n_tiles) * 128;
    const int m0 = (g / n_tiles) * 128;

    f32x4 acc[4][4];
#pragma unroll
    for (int i = 0; i < 4; ++i)
#pragma unroll
        for (int j = 0; j < 4; ++j) { f32x4 z = {0.f, 0.f, 0.f, 0.f}; acc[i][j] = z; }

    for (int k0 = 0; k0 < K; k0 += 64) {
        // ---- stage A,B 128x64 tiles: 4 sites x 256 thr x 16 B each ----
#pragma unroll
        for (int s = 0; s < 4; ++s) {
            int li   = s * 256 + tid;          // chunk 0..1023
            int row  = (li & 511) >> 2;        // 0..127
            int ke   = (li >> 9) * 32 + (li & 3) * 8;  // k element offset 0..63
            const __hip_bfloat16* ga = A + (size_t)(m0 + row) * K + k0 + ke;
            const __hip_bfloat16* gb = B + (size_t)(n0 + row) * K + k0 + ke;
            int chunk = s * 256 + (tid & ~63); // wave-uniform base chunk
            __builtin_amdgcn_global_load_lds(
                (const __attribute__((address_space(1))) unsigned int*)ga,
                (__attribute__((address_space(3))) unsigned int*)(As + chunk * 8),
                16, 0, 0);
            __builtin_amdgcn_global_load_lds(
                (const __attribute__((address_space(1))) unsigned int*)gb,
                (__attribute__((address_space(3))) unsigned int*)(Bs + chunk * 8),
                16, 0, 0);
        }
        __syncthreads();

        // ---- two 32-k halves: fragments + MFMA ----
#pragma unroll
        for (int kh = 0; kh < 2; ++kh) {
            const short* ap = (const short*)As + kh * 4096;
            const short* bp = (const short*)Bs + kh * 4096;
            short8 af[4], bf[4];
#pragma unroll
            for (int mt = 0; mt < 4; ++mt) {
                int row = wr * 64 + mt * 16 + l16;
                af[mt] = *(const short8*)(ap + row * 32 + quad * 8);
            }
#pragma unroll
            for (int nt = 0; nt < 4; ++nt) {
                int row = wc * 64 + nt * 16 + l16;
                bf[nt] = *(const short8*)(bp + row * 32 + quad * 8);
            }
#pragma unroll
            for (int mt = 0; mt < 4; ++mt)
#pragma unroll
                for (int nt = 0; nt < 4; ++nt)
                    acc[mt][nt] = __builtin_amdgcn_mfma_f32_16x16x32_bf16(
                        af[mt], bf[nt], acc[mt][nt], 0, 0, 0);
        }
        __syncthreads();
    }

    // ---- epilogue: C row = quad*4 + r, col = l16 ----
#pragma unroll
    for (int nt = 0; nt < 4; ++nt) {
        int n = n0 + wc * 64 + nt * 16 + l16;
        float bv = bias[n];
#pragma unroll
        for (int mt = 0; mt < 4; ++mt) {
            int mbase = m0 + wr * 64 + mt * 16 + quad * 4;
#pragma unroll
            for (int r = 0; r < 4; ++r) {
                float v = acc[mt][nt][r] + bv;
                v = v > 0.0f ? v : 0.0f;
                out[(size_t)(mbase + r) * N + n] = (__hip_bfloat16)v;
            }
        }
    }
}

// ---------------------------------------------------------------------------
// Head: one wave per line: logits[l][n] = sum_k x2[l][k]*w3[n][k] + b3[n]
// ---------------------------------------------------------------------------
__global__ __launch_bounds__(256) void head_kernel(
    const __hip_bfloat16* __restrict__ x2,  // (N_LINES, 1024) bf16
    const float* __restrict__ w3,           // (3, 1024)
    const float* __restrict__ b3,           // (3)
    float* __restrict__ out)                // (N_LINES, 3)
{
    const int gtid = blockIdx.x * blockDim.x + threadIdx.x;
    const int l = gtid >> 6;
    const int lane = threadIdx.x & 63;
    if (l >= N_LINES) return;
    const __hip_bfloat16* xr = x2 + (size_t)l * DIM_FC;
    float s0 = 0.0f, s1 = 0.0f, s2 = 0.0f;
#pragma unroll
    for (int it = 0; it < 4; ++it) {
        int k = it * 256 + lane * 4;
        ushort4 xv = *(const ushort4*)(xr + k);
        float x0 = __uint_as_float((unsigned)xv.x << 16);
        float x1 = __uint_as_float((unsigned)xv.y << 16);
        float x2v = __uint_as_float((unsigned)xv.z << 16);
        float x3 = __uint_as_float((unsigned)xv.w << 16);
        float4 wa = *(const float4*)(w3 + 0 * DIM_FC + k);
        float4 wb = *(const float4*)(w3 + 1 * DIM_FC + k);
        float4 wc = *(const float4*)(w3 + 2 * DIM_FC + k);
        s0 += x0 * wa.x + x1 * wa.y + x2v * wa.z + x3 * wa.w;
        s1 += x0 * wb.x + x1 * wb.y + x2v * wb.z + x3 * wb.w;
        s2 += x0 * wc.x + x1 * wc.y + x2v * wc.z + x3 * wc.w;
    }
#pragma unroll
    for (int off = 32; off > 0; off >>= 1) {
        s0 += __shfl_xor(s0, off);
        s1 += __shfl_xor(s1, off);
        s2 += __shfl_xor(s2, off);
    }
    if (lane == 0) {
        out[(size_t)l * 3 + 0] = s0 + b3[0];
        out[(size_t)l * 3 + 1] = s1 + b3[1];
        out[(size_t)l * 3 + 2] = s2 + b3[2];
    }
}

// ---------------------------------------------------------------------------
extern "C" void kernel_launch(void* const* d_in, const int* in_sizes, int n_in,
                              void* d_out, int out_size, void* d_ws, size_t ws_size,
                              hipStream_t stream) {
    const float* features = (const float*)d_in[0];  // (1,256,128,128)
    const float* lines    = (const float*)d_in[1];  // (16000,4)
    const float* w_fc1    = (const float*)d_in[2];  // (128,256)
    const float* b_fc1    = (const float*)d_in[3];  // (128)
    const float* w1       = (const float*)d_in[4];  // (1024,1024)
    const float* b1       = (const float*)d_in[5];  // (1024)
    const float* w2       = (const float*)d_in[6];  // (1024,1024)
    const float* b2       = (const float*)d_in[7];  // (1024)
    const float* w3       = (const float*)d_in[8];  // (3,1024)
    const float* b3       = (const float*)d_in[9];  // (3)
    float* out = (float*)d_out;

    char* ws = (char*)d_ws;
    __hip_bfloat16* loi    = (__hip_bfloat16*)ws;
    __hip_bfloat16* featb  = (__hip_bfloat16*)(ws + (size_t)8 * 1024 * 1024);
    __hip_bfloat16* x1b    = (__hip_bfloat16*)(ws + (size_t)40 * 1024 * 1024);
    __hip_bfloat16* x2b    = featb;   // reuse (featb dead after GEMM1)
    __hip_bfloat16* w1b    = (__hip_bfloat16*)(ws + (size_t)72 * 1024 * 1024);
    __hip_bfloat16* w2b    = (__hip_bfloat16*)(ws + (size_t)74 * 1024 * 1024);
    __hip_bfloat16* featsT = (__hip_bfloat16*)(ws + (size_t)76 * 1024 * 1024);
    __hip_bfloat16* wfc1b  = (__hip_bfloat16*)(ws + (size_t)84 * 1024 * 1024);

    // 0) all prep in one dispatch
    prep_kernel<<<dim3(3104), 256, 0, stream>>>(
        features, featsT, w1, w1b, w2, w2b, w_fc1, wfc1b);

    // 1) conv1x1 as MFMA GEMM (grid 128, 1 n-tile, K=256 -> 4 iters)
    mfma_gemm<<<dim3(NPIX / 128), 256, 0, stream>>>(
        featsT, wfc1b, b_fc1, loi, NPIX, DIM_LOI, C_IN, 1);

    // 2) line pooling -> featb (16000,1024) bf16, k' = p*128+c
    pool_kernel<<<dim3(N_LINES / 4), 256, 0, stream>>>(loi, lines, featb);

    // 3) x1 = relu(feat @ w1p^T + b1)   grid 1000 = 125 m x 8 n
    mfma_gemm<<<dim3((N_LINES / 128) * (DIM_FC / 128)), 256, 0, stream>>>(
        featb, w1b, b1, x1b, N_LINES, DIM_FC, DIM_FC, DIM_FC / 128);

    // 4) x2 = relu(x1 @ w2^T + b2)
    mfma_gemm<<<dim3((N_LINES / 128) * (DIM_FC / 128)), 256, 0, stream>>>(
        x1b, w2b, b2, x2b, N_LINES, DIM_FC, DIM_FC, DIM_FC / 128);

    // 5) logits = x2 @ w3^T + b3
    head_kernel<<<dim3((N_LINES * 64 + 255) / 256), 256, 0, stream>>>(x2b, w3, b3, out);
}

// Round 12
// 211.532 us; speedup vs baseline: 1.2880x; 1.0412x over previous
//
#include <hip/hip_runtime.h>
#include <hip/hip_bf16.h>
#include <math.h>

// Problem dims (fixed)
#define C_IN 256
#define HW 128          // H = W = 128
#define NPIX (HW*HW)    // 16384
#define DIM_LOI 128
#define N_LINES 16000
#define N_PTS0 32
#define N_PTS1 8
#define DIM_FC 1024
#define N_LABELS 3

typedef __attribute__((ext_vector_type(8))) short short8;   // 8 bf16 = 4 VGPRs
typedef __attribute__((ext_vector_type(4))) float f32x4;

// ---------------------------------------------------------------------------
// prep_kernel: all input conversions in ONE dispatch (branch on blockIdx).
//  [0,1024)    : transpose+bf16 features (256,16384) -> featsT (16384,256)
//  [1024,2048) : permute_w1  k=c*8+p -> k'=p*128+c, fp32->bf16
//  [2048,3072) : to_bf16 w2
//  [3072,3104) : to_bf16 w_fc1
// ---------------------------------------------------------------------------
__global__ __launch_bounds__(256) void prep_kernel(
    const float* __restrict__ feats, __hip_bfloat16* __restrict__ featsT,
    const float* __restrict__ w1,    __hip_bfloat16* __restrict__ w1p,
    const float* __restrict__ w2,    __hip_bfloat16* __restrict__ w2b,
    const float* __restrict__ wfc1,  __hip_bfloat16* __restrict__ wfc1b)
{
    __shared__ float tile[64][65];
    const int b = blockIdx.x;
    const int t = threadIdx.x;

    if (b < 1024) {
        // ---- transpose features ----
        const int p0 = (b & 255) * 64;
        const int c0 = (b >> 8) * 64;
#pragma unroll
        for (int i = 0; i < 4; ++i) {
            int c = (t >> 4) + i * 16;
            int p4 = (t & 15) * 4;
            float4 v = *(const float4*)(feats + (size_t)(c0 + c) * NPIX + p0 + p4);
            tile[c][p4 + 0] = v.x;
            tile[c][p4 + 1] = v.y;
            tile[c][p4 + 2] = v.z;
            tile[c][p4 + 3] = v.w;
        }
        __syncthreads();
#pragma unroll
        for (int i = 0; i < 2; ++i) {
            int p = (t >> 3) + i * 32;
            int cc = (t & 7) * 8;
            union { __hip_bfloat16 h[8]; uint4 u4; } pk;
#pragma unroll
            for (int j = 0; j < 8; ++j) pk.h[j] = __float2bfloat16(tile[cc + j][p]);
            *(uint4*)(featsT + (size_t)(p0 + p) * C_IN + c0 + cc) = pk.u4;
        }
    } else if (b < 2048) {
        // ---- permute w1 row ----
        float* row = &tile[0][0];
        const int n = b - 1024;
        ((float4*)row)[t] = ((const float4*)(w1 + (size_t)n * 1024))[t];
        __syncthreads();
        unsigned int* dst = (unsigned int*)(w1p + (size_t)n * 1024);
#pragma unroll
        for (int pass = 0; pass < 2; ++pass) {
            int j = pass * 256 + t;
            int k0 = 2 * j, k1 = 2 * j + 1;
            float v0 = row[(k0 & 127) * 8 + (k0 >> 7)];
            float v1 = row[(k1 & 127) * 8 + (k1 >> 7)];
            union { __hip_bfloat16 h[2]; unsigned int u; } pk;
            pk.h[0] = __float2bfloat16(v0);
            pk.h[1] = __float2bfloat16(v1);
            dst[j] = pk.u;
        }
    } else if (b < 3072) {
        int i = (b - 2048) * 256 + t;     // float4 index into w2
        float4 v = *(const float4*)(w2 + (size_t)i * 4);
        union { __hip_bfloat16 h[4]; uint2 u; } pk;
        pk.h[0] = __float2bfloat16(v.x);
        pk.h[1] = __float2bfloat16(v.y);
        pk.h[2] = __float2bfloat16(v.z);
        pk.h[3] = __float2bfloat16(v.w);
        *(uint2*)(w2b + (size_t)i * 4) = pk.u;
    } else {
        int i = (b - 3072) * 256 + t;     // float4 index into w_fc1 (8192 total)
        float4 v = *(const float4*)(wfc1 + (size_t)i * 4);
        union { __hip_bfloat16 h[4]; uint2 u; } pk;
        pk.h[0] = __float2bfloat16(v.x);
        pk.h[1] = __float2bfloat16(v.y);
        pk.h[2] = __float2bfloat16(v.z);
        pk.h[3] = __float2bfloat16(v.w);
        *(uint2*)(wfc1b + (size_t)i * 4) = pk.u;
    }
}

// ---------------------------------------------------------------------------
// Line pool v3. 256 thr = 4 lines x 1 wave; wave = 4 quarter-waves of 16:
// quarter qd handles output points {qd, qd+4}; lane t16 owns channels
// 8*t16..8*t16+7 via uint4 gathers (one 256-B corner row per 16 lanes).
// feat layout k' = p*128 + c (matches permuted w1).
// ---------------------------------------------------------------------------
__global__ __launch_bounds__(256) void pool_kernel(
    const __hip_bfloat16* __restrict__ loi,   // (NPIX, 128) bf16 channel-last
    const float* __restrict__ lines,          // (N_LINES, 4)
    __hip_bfloat16* __restrict__ feat)        // (N_LINES, 1024), k' = p*128+c
{
    __shared__ int   offs[4][N_PTS0][4];      // uint4-index base (pix*16)
    __shared__ float wts[4][N_PTS0][4];
    const int g    = threadIdx.x >> 6;   // line group in block
    const int lane = threadIdx.x & 63;
    const int qd   = lane >> 4;          // quarter: output points qd, qd+4
    const int t16  = lane & 15;          // channel group 8*t16..8*t16+7
    const int l    = blockIdx.x * 4 + g;

    if (lane < N_PTS0) {
        int j = lane;
        float tt = (float)j * (1.0f / 31.0f);
        float U0 = lines[4 * l + 0], U1 = lines[4 * l + 1];
        float V0 = lines[4 * l + 2], V1 = lines[4 * l + 3];
        float px = U0 * tt + V0 * (1.0f - tt) - 0.5f;
        float py = U1 * tt + V1 * (1.0f - tt) - 0.5f;
        float px0 = fminf(fmaxf(floorf(px), 0.0f), 127.0f);
        float py0 = fminf(fmaxf(floorf(py), 0.0f), 127.0f);
        float px1 = fminf(fmaxf(px0 + 1.0f, 0.0f), 127.0f);
        float py1 = fminf(fmaxf(py0 + 1.0f, 0.0f), 127.0f);
        int ix0 = (int)px0, iy0 = (int)py0, ix1 = (int)px1, iy1 = (int)py1;
        float wx0 = px1 - px, wx1 = px - px0;
        float wy0 = py1 - py, wy1 = py - py0;
        offs[g][j][0] = (iy0 * HW + ix0) * 16;
        offs[g][j][1] = (iy1 * HW + ix0) * 16;
        offs[g][j][2] = (iy0 * HW + ix1) * 16;
        offs[g][j][3] = (iy1 * HW + ix1) * 16;
        wts[g][j][0] = wy0 * wx0;
        wts[g][j][1] = wy1 * wx0;
        wts[g][j][2] = wy0 * wx1;
        wts[g][j][3] = wy1 * wx1;
    }
    __syncthreads();

    const uint4* loi4 = (const uint4*)loi;
    uint4* featw = (uint4*)(feat + (size_t)l * (N_PTS1 * DIM_LOI));

#pragma unroll
    for (int p = 0; p < 2; ++p) {
        const int point = qd + 4 * p;   // 0..7
        float b0 = -INFINITY, b1 = -INFINITY, b2 = -INFINITY, b3 = -INFINITY;
        float b4 = -INFINITY, b5 = -INFINITY, b6 = -INFINITY, b7 = -INFINITY;
#pragma unroll
        for (int q = 0; q < 4; ++q) {
            int j = point * 4 + q;
            uint4 v0 = loi4[offs[g][j][0] + t16];
            uint4 v1 = loi4[offs[g][j][1] + t16];
            uint4 v2 = loi4[offs[g][j][2] + t16];
            uint4 v3 = loi4[offs[g][j][3] + t16];
            float w0 = wts[g][j][0], w1 = wts[g][j][1];
            float w2 = wts[g][j][2], w3 = wts[g][j][3];
            float s;
            s = w0 * __uint_as_float(v0.x << 16) + w1 * __uint_as_float(v1.x << 16)
              + w2 * __uint_as_float(v2.x << 16) + w3 * __uint_as_float(v3.x << 16);
            b0 = fmaxf(b0, s);
            s = w0 * __uint_as_float(v0.x & 0xffff0000u) + w1 * __uint_as_float(v1.x & 0xffff0000u)
              + w2 * __uint_as_float(v2.x & 0xffff0000u) + w3 * __uint_as_float(v3.x & 0xffff0000u);
            b1 = fmaxf(b1, s);
            s = w0 * __uint_as_float(v0.y << 16) + w1 * __uint_as_float(v1.y << 16)
              + w2 * __uint_as_float(v2.y << 16) + w3 * __uint_as_float(v3.y << 16);
            b2 = fmaxf(b2, s);
            s = w0 * __uint_as_float(v0.y & 0xffff0000u) + w1 * __uint_as_float(v1.y & 0xffff0000u)
              + w2 * __uint_as_float(v2.y & 0xffff0000u) + w3 * __uint_as_float(v3.y & 0xffff0000u);
            b3 = fmaxf(b3, s);
            s = w0 * __uint_as_float(v0.z << 16) + w1 * __uint_as_float(v1.z << 16)
              + w2 * __uint_as_float(v2.z << 16) + w3 * __uint_as_float(v3.z << 16);
            b4 = fmaxf(b4, s);
            s = w0 * __uint_as_float(v0.z & 0xffff0000u) + w1 * __uint_as_float(v1.z & 0xffff0000u)
              + w2 * __uint_as_float(v2.z & 0xffff0000u) + w3 * __uint_as_float(v3.z & 0xffff0000u);
            b5 = fmaxf(b5, s);
            s = w0 * __uint_as_float(v0.w << 16) + w1 * __uint_as_float(v1.w << 16)
              + w2 * __uint_as_float(v2.w << 16) + w3 * __uint_as_float(v3.w << 16);
            b6 = fmaxf(b6, s);
            s = w0 * __uint_as_float(v0.w & 0xffff0000u) + w1 * __uint_as_float(v1.w & 0xffff0000u)
              + w2 * __uint_as_float(v2.w & 0xffff0000u) + w3 * __uint_as_float(v3.w & 0xffff0000u);
            b7 = fmaxf(b7, s);
        }
        union { __hip_bfloat16 hh[8]; uint4 u; } pk;
        pk.hh[0] = __float2bfloat16(b0);
        pk.hh[1] = __float2bfloat16(b1);
        pk.hh[2] = __float2bfloat16(b2);
        pk.hh[3] = __float2bfloat16(b3);
        pk.hh[4] = __float2bfloat16(b4);
        pk.hh[5] = __float2bfloat16(b5);
        pk.hh[6] = __float2bfloat16(b6);
        pk.hh[7] = __float2bfloat16(b7);
        featw[point * 16 + t16] = pk.u;   // elements point*128 + 8*t16 ..+7
    }
}

// ---------------------------------------------------------------------------
// MFMA bf16 GEMM, BK=64, DOUBLE-BUFFERED prefetch.
// 128x128 tile, 4 waves 2x2, each wave 4x4 of 16x16x32 MFMA (R6 compute core).
// Two 32-KB LDS buffers; stage(kt+1 -> nxt) is issued BEFORE compute(cur),
// so the vmcnt(0) drain at the loop barrier overlaps the HBM/L2 fill with
// the MFMA work instead of exposing it (the single-buffer structure's
// dominant stall at K=1024: all 8 A-sharing blocks miss L2 simultaneously).
// XCD-aware swizzle: lid%8 = XCD, n fastest -> A-tile reused within one XCD.
// ---------------------------------------------------------------------------
__global__ __launch_bounds__(256) void mfma_gemm(
    const __hip_bfloat16* __restrict__ A,   // (M, K) row-major
    const __hip_bfloat16* __restrict__ B,   // (N, K) row-major (= B^T)
    const float* __restrict__ bias,         // (N)
    __hip_bfloat16* __restrict__ out,       // (M, N)
    int M, int N, int K, int n_tiles)
{
    __shared__ __hip_bfloat16 As[2][128 * 64];   // 32 KB
    __shared__ __hip_bfloat16 Bs[2][128 * 64];   // 32 KB
    const int tid  = threadIdx.x;
    const int lane = tid & 63;
    const int wave = tid >> 6;
    const int wr = wave >> 1, wc = wave & 1;    // 2x2 wave grid
    const int quad = lane >> 4;
    const int l16  = lane & 15;

    // XCD-aware relabel (grid must be divisible by 8)
    const int lid = blockIdx.x;
    const int per = gridDim.x >> 3;
    const int g   = (lid & 7) * per + (lid >> 3);
    const int n0 = (g % n_tiles) * 128;
    const int m0 = (g / n_tiles) * 128;

    // staging addresses (loop-invariant parts)
    const int srow = (tid & 255) >> 2;               // unused helper
    (void)srow;

    f32x4 acc[4][4];
#pragma unroll
    for (int i = 0; i < 4; ++i)
#pragma unroll
        for (int j = 0; j < 4; ++j) { f32x4 z = {0.f, 0.f, 0.f, 0.f}; acc[i][j] = z; }

    // ---- stage helper (4 sites x 256 thr x 16 B per matrix) ----
    auto stage = [&](int k0, int buf) {
#pragma unroll
        for (int s = 0; s < 4; ++s) {
            int li   = s * 256 + tid;          // chunk 0..1023
            int row  = (li & 511) >> 2;        // 0..127
            int ke   = (li >> 9) * 32 + (li & 3) * 8;  // k element offset 0..63
            const __hip_bfloat16* ga = A + (size_t)(m0 + row) * K + k0 + ke;
            const __hip_bfloat16* gb = B + (size_t)(n0 + row) * K + k0 + ke;
            int chunk = s * 256 + (tid & ~63); // wave-uniform base chunk
            __builtin_amdgcn_global_load_lds(
                (const __attribute__((address_space(1))) unsigned int*)ga,
                (__attribute__((address_space(3))) unsigned int*)(As[buf] + chunk * 8),
                16, 0, 0);
            __builtin_amdgcn_global_load_lds(
                (const __attribute__((address_space(1))) unsigned int*)gb,
                (__attribute__((address_space(3))) unsigned int*)(Bs[buf] + chunk * 8),
                16, 0, 0);
        }
    };

    const int nk = K >> 6;
    stage(0, 0);
    __syncthreads();                 // buffer 0 ready

    for (int kt = 0; kt < nk; ++kt) {
        const int cur = kt & 1;
        if (kt + 1 < nk) stage((kt + 1) << 6, cur ^ 1);   // async prefetch

        // ---- compute from buffer cur: two 32-k halves ----
#pragma unroll
        for (int kh = 0; kh < 2; ++kh) {
            const short* ap = (const short*)As[cur] + kh * 4096;
            const short* bp = (const short*)Bs[cur] + kh * 4096;
            short8 af[4], bf[4];
#pragma unroll
            for (int mt = 0; mt < 4; ++mt) {
                int row = wr * 64 + mt * 16 + l16;
                af[mt] = *(const short8*)(ap + row * 32 + quad * 8);
            }
#pragma unroll
            for (int nt = 0; nt < 4; ++nt) {
                int row = wc * 64 + nt * 16 + l16;
                bf[nt] = *(const short8*)(bp + row * 32 + quad * 8);
            }
#pragma unroll
            for (int mt = 0; mt < 4; ++mt)
#pragma unroll
                for (int nt = 0; nt < 4; ++nt)
                    acc[mt][nt] = __builtin_amdgcn_mfma_f32_16x16x32_bf16(
                        af[mt], bf[nt], acc[mt][nt], 0, 0, 0);
        }
        __syncthreads();   // drains prefetch (overlapped) + releases cur buffer
    }

    // ---- epilogue: C row = quad*4 + r, col = l16 ----
#pragma unroll
    for (int nt = 0; nt < 4; ++nt) {
        int n = n0 + wc * 64 + nt * 16 + l16;
        float bv = bias[n];
#pragma unroll
        for (int mt = 0; mt < 4; ++mt) {
            int mbase = m0 + wr * 64 + mt * 16 + quad * 4;
#pragma unroll
            for (int r = 0; r < 4; ++r) {
                float v = acc[mt][nt][r] + bv;
                v = v > 0.0f ? v : 0.0f;
                out[(size_t)(mbase + r) * N + n] = (__hip_bfloat16)v;
            }
        }
    }
}

// ---------------------------------------------------------------------------
// Head: one wave per line: logits[l][n] = sum_k x2[l][k]*w3[n][k] + b3[n]
// ---------------------------------------------------------------------------
__global__ __launch_bounds__(256) void head_kernel(
    const __hip_bfloat16* __restrict__ x2,  // (N_LINES, 1024) bf16
    const float* __restrict__ w3,           // (3, 1024)
    const float* __restrict__ b3,           // (3)
    float* __restrict__ out)                // (N_LINES, 3)
{
    const int gtid = blockIdx.x * blockDim.x + threadIdx.x;
    const int l = gtid >> 6;
    const int lane = threadIdx.x & 63;
    if (l >= N_LINES) return;
    const __hip_bfloat16* xr = x2 + (size_t)l * DIM_FC;
    float s0 = 0.0f, s1 = 0.0f, s2 = 0.0f;
#pragma unroll
    for (int it = 0; it < 4; ++it) {
        int k = it * 256 + lane * 4;
        ushort4 xv = *(const ushort4*)(xr + k);
        float x0 = __uint_as_float((unsigned)xv.x << 16);
        float x1 = __uint_as_float((unsigned)xv.y << 16);
        float x2v = __uint_as_float((unsigned)xv.z << 16);
        float x3 = __uint_as_float((unsigned)xv.w << 16);
        float4 wa = *(const float4*)(w3 + 0 * DIM_FC + k);
        float4 wb = *(const float4*)(w3 + 1 * DIM_FC + k);
        float4 wc = *(const float4*)(w3 + 2 * DIM_FC + k);
        s0 += x0 * wa.x + x1 * wa.y + x2v * wa.z + x3 * wa.w;
        s1 += x0 * wb.x + x1 * wb.y + x2v * wb.z + x3 * wb.w;
        s2 += x0 * wc.x + x1 * wc.y + x2v * wc.z + x3 * wc.w;
    }
#pragma unroll
    for (int off = 32; off > 0; off >>= 1) {
        s0 += __shfl_xor(s0, off);
        s1 += __shfl_xor(s1, off);
        s2 += __shfl_xor(s2, off);
    }
    if (lane == 0) {
        out[(size_t)l * 3 + 0] = s0 + b3[0];
        out[(size_t)l * 3 + 1] = s1 + b3[1];
        out[(size_t)l * 3 + 2] = s2 + b3[2];
    }
}

// ---------------------------------------------------------------------------
extern "C" void kernel_launch(void* const* d_in, const int* in_sizes, int n_in,
                              void* d_out, int out_size, void* d_ws, size_t ws_size,
                              hipStream_t stream) {
    const float* features = (const float*)d_in[0];  // (1,256,128,128)
    const float* lines    = (const float*)d_in[1];  // (16000,4)
    const float* w_fc1    = (const float*)d_in[2];  // (128,256)
    const float* b_fc1    = (const float*)d_in[3];  // (128)
    const float* w1       = (const float*)d_in[4];  // (1024,1024)
    const float* b1       = (const float*)d_in[5];  // (1024)
    const float* w2       = (const float*)d_in[6];  // (1024,1024)
    const float* b2       = (const float*)d_in[7];  // (1024)
    const float* w3       = (const float*)d_in[8];  // (3,1024)
    const float* b3       = (const float*)d_in[9];  // (3)
    float* out = (float*)d_out;

    char* ws = (char*)d_ws;
    __hip_bfloat16* loi    = (__hip_bfloat16*)ws;
    __hip_bfloat16* featb  = (__hip_bfloat16*)(ws + (size_t)8 * 1024 * 1024);
    __hip_bfloat16* x1b    = (__hip_bfloat16*)(ws + (size_t)40 * 1024 * 1024);
    __hip_bfloat16* x2b    = featb;   // reuse (featb dead after GEMM1)
    __hip_bfloat16* w1b    = (__hip_bfloat16*)(ws + (size_t)72 * 1024 * 1024);
    __hip_bfloat16* w2b    = (__hip_bfloat16*)(ws + (size_t)74 * 1024 * 1024);
    __hip_bfloat16* featsT = (__hip_bfloat16*)(ws + (size_t)76 * 1024 * 1024);
    __hip_bfloat16* wfc1b  = (__hip_bfloat16*)(ws + (size_t)84 * 1024 * 1024);

    // 0) all prep in one dispatch
    prep_kernel<<<dim3(3104), 256, 0, stream>>>(
        features, featsT, w1, w1b, w2, w2b, w_fc1, wfc1b);

    // 1) conv1x1 as MFMA GEMM (grid 128, 1 n-tile, K=256 -> 4 iters)
    mfma_gemm<<<dim3(NPIX / 128), 256, 0, stream>>>(
        featsT, wfc1b, b_fc1, loi, NPIX, DIM_LOI, C_IN, 1);

    // 2) line pooling -> featb (16000,1024) bf16, k' = p*128+c
    pool_kernel<<<dim3(N_LINES / 4), 256, 0, stream>>>(loi, lines, featb);

    // 3) x1 = relu(feat @ w1p^T + b1)   grid 1000 = 125 m x 8 n
    mfma_gemm<<<dim3((N_LINES / 128) * (DIM_FC / 128)), 256, 0, stream>>>(
        featb, w1b, b1, x1b, N_LINES, DIM_FC, DIM_FC, DIM_FC / 128);

    // 4) x2 = relu(x1 @ w2^T + b2)
    mfma_gemm<<<dim3((N_LINES / 128) * (DIM_FC / 128)), 256, 0, stream>>>(
        x1b, w2b, b2, x2b, N_LINES, DIM_FC, DIM_FC, DIM_FC / 128);

    // 5) logits = x2 @ w3^T + b3
    head_kernel<<<dim3((N_LINES * 64 + 255) / 256), 256, 0, stream>>>(x2b, w3, b3, out);
}